// Round 5
// baseline (122.862 us; speedup 1.0000x reference)
//
#include <hip/hip_runtime.h>
#include <math.h>

#define NB 4      // batch
#define TD 128    // T_DEC
#define SE 1024   // S_ENC
#define DD 512    // D
#define UN 128    // UNITS

// tanh(x) = 1 - 2/(exp(2x)+1). exp via __expf (v_exp); rcp via v_rcp.
// Stable at +-inf; rel err ~1e-5 << 3e-3 tolerance.

// ---------------------------------------------------------------------------
// K1: projections. 512 thr (8 waves), 16 rows/WG.
//   blocks 0..255   : enc rows -> wencT[b][u][s] (direct transposed write)
//   blocks 256..287 : dec rows -> wdec[bt][u]    (row-major)
// Thread = (u = tx&127, rg = tx>>7): 4 rows x 1 u, K=512 in 8 chunks of 64.
// W chunk (64k x 128u = 32 KB) staged in LDS; reads are 2-way bank-aliased
// (free). enc reads are wave-uniform float4 broadcasts (L1).
__global__ __launch_bounds__(512, 1) void k_proj(const float* __restrict__ enc,
                                                 const float* __restrict__ dec,
                                                 const float* __restrict__ W1,
                                                 const float* __restrict__ b1,
                                                 const float* __restrict__ W2,
                                                 const float* __restrict__ b2,
                                                 float* __restrict__ wencT,
                                                 float* __restrict__ wdec) {
  __shared__ __align__(16) float Wl[64 * UN];   // 32 KB

  const int tx = threadIdx.x;
  const int u = tx & 127;
  const int rg = tx >> 7;              // 0..3, rows rg*4..rg*4+3
  const int blk = blockIdx.x;
  const bool is_enc = blk < 256;       // 256 enc blocks (4096 rows), 32 dec blocks (512 rows)
  const int row_base = is_enc ? blk * 16 : (blk - 256) * 16;
  const float* src = (is_enc ? enc : dec) + (size_t)row_base * DD;
  const float* W = is_enc ? W1 : W2;
  const float* bias = is_enc ? b1 : b2;

  const float* erow = src + (size_t)(rg * 4) * DD;
  float acc[4] = {};

  for (int c = 0; c < 8; ++c) {
    // stage W[c*64 .. c*64+63][0..127] into LDS: 2048 float4, 4 per thread
    const float* Wc = W + (size_t)c * 64 * UN;
#pragma unroll
    for (int i = 0; i < 4; ++i) {
      const int idx = (i * 512 + tx) * 4;
      *(float4*)&Wl[idx] = *(const float4*)(Wc + idx);
    }
    __syncthreads();
    const int kb = c * 64;
    for (int k0 = 0; k0 < 64; k0 += 4) {
      float4 e[4];
#pragma unroll
      for (int r = 0; r < 4; ++r)
        e[r] = *(const float4*)(erow + (size_t)r * DD + kb + k0);
#pragma unroll
      for (int kk = 0; kk < 4; ++kk) {
        const float w = Wl[(k0 + kk) * UN + u];
#pragma unroll
        for (int r = 0; r < 4; ++r)
          acc[r] = fmaf(((const float*)&e[r])[kk], w, acc[r]);
      }
    }
    __syncthreads();
  }

  const float bb = bias[u];
  if (is_enc) {
    const int b = row_base >> 10;
    const int s0 = row_base & 1023;
    float4 o = make_float4(acc[0] + bb, acc[1] + bb, acc[2] + bb, acc[3] + bb);
    *(float4*)(wencT + (size_t)(b * UN + u) * SE + s0 + rg * 4) = o;
  } else {
#pragma unroll
    for (int r = 0; r < 4; ++r)
      wdec[(size_t)(row_base + rg * 4 + r) * UN + u] = acc[r] + bb;
  }
}

// ---------------------------------------------------------------------------
// K2: scores + softmax. One WG (512 thr) per (b, t-pair): grid 256.
// Thread: 4 consecutive s (float4 coalesced stream over u) x 2 t x 64 u
// (u-half by wave group). wencT[b][u][s] stream is fully coalesced; wd/v are
// LDS broadcasts. v_b skipped (softmax shift-invariant).
__global__ __launch_bounds__(512, 1) void k_score(const float* __restrict__ wdec,
                                                  const float* __restrict__ v,
                                                  const float* __restrict__ wencT,
                                                  float* __restrict__ attn) {
  __shared__ __align__(16) float wd2[2][UN];        // 2*wdec row
  __shared__ __align__(16) float vsh[UN];
  __shared__ __align__(16) float parts[2][2][SE];   // [uhalf][tt][s]  16 KB
  __shared__ float redM[2][4], redS[2][4];

  const int wg = blockIdx.x;          // 0..255
  const int b = wg >> 6;
  const int t0 = (wg & 63) * 2;
  const int bt0 = b * TD + t0;
  const int tx = threadIdx.x;

  if (tx < 2 * UN) {
    const int tt = tx >> 7, u = tx & 127;
    wd2[tt][u] = 2.0f * wdec[(size_t)(bt0 + tt) * UN + u];
    if (tx < UN) vsh[tx] = v[tx];
  }
  __syncthreads();

  const int sq = tx & 255;            // s-quad 0..255
  const int uh = tx >> 8;             // u half 0/1
  const float* wp = wencT + (size_t)(b * UN + uh * 64) * SE + sq * 4;

  float a0[4] = {}, a1[4] = {};
  for (int ui = 0; ui < 64; ++ui) {
    const int u = uh * 64 + ui;
    const float4 w = *(const float4*)(wp + (size_t)ui * SE);
    const float vv = vsh[u];
    const float d0 = wd2[0][u];
    const float d1 = wd2[1][u];
#pragma unroll
    for (int j = 0; j < 4; ++j) {
      const float wj = ((const float*)&w)[j];
      float e0 = __expf(fmaf(wj, 2.0f, d0));
      float t0v = fmaf(-2.0f, __builtin_amdgcn_rcpf(e0 + 1.0f), 1.0f);
      a0[j] = fmaf(vv, t0v, a0[j]);
      float e1 = __expf(fmaf(wj, 2.0f, d1));
      float t1v = fmaf(-2.0f, __builtin_amdgcn_rcpf(e1 + 1.0f), 1.0f);
      a1[j] = fmaf(vv, t1v, a1[j]);
    }
  }
  *(float4*)&parts[uh][0][sq * 4] = make_float4(a0[0], a0[1], a0[2], a0[3]);
  *(float4*)&parts[uh][1][sq * 4] = make_float4(a1[0], a1[1], a1[2], a1[3]);
  __syncthreads();

  float sc0[4], sc1[4];
  if (tx < 256) {
    const float4 p00 = *(const float4*)&parts[0][0][tx * 4];
    const float4 p10 = *(const float4*)&parts[1][0][tx * 4];
    const float4 p01 = *(const float4*)&parts[0][1][tx * 4];
    const float4 p11 = *(const float4*)&parts[1][1][tx * 4];
    sc0[0] = p00.x + p10.x; sc0[1] = p00.y + p10.y;
    sc0[2] = p00.z + p10.z; sc0[3] = p00.w + p10.w;
    sc1[0] = p01.x + p11.x; sc1[1] = p01.y + p11.y;
    sc1[2] = p01.z + p11.z; sc1[3] = p01.w + p11.w;
    float m0 = fmaxf(fmaxf(sc0[0], sc0[1]), fmaxf(sc0[2], sc0[3]));
    float m1 = fmaxf(fmaxf(sc1[0], sc1[1]), fmaxf(sc1[2], sc1[3]));
#pragma unroll
    for (int off = 32; off; off >>= 1) {
      m0 = fmaxf(m0, __shfl_xor(m0, off));
      m1 = fmaxf(m1, __shfl_xor(m1, off));
    }
    if ((tx & 63) == 0) { redM[0][tx >> 6] = m0; redM[1][tx >> 6] = m1; }
  }
  __syncthreads();
  float p0[4], p1[4];
  if (tx < 256) {
    const float m0 = fmaxf(fmaxf(redM[0][0], redM[0][1]), fmaxf(redM[0][2], redM[0][3]));
    const float m1 = fmaxf(fmaxf(redM[1][0], redM[1][1]), fmaxf(redM[1][2], redM[1][3]));
    float s0 = 0.f, s1 = 0.f;
#pragma unroll
    for (int j = 0; j < 4; ++j) {
      p0[j] = __expf(sc0[j] - m0); s0 += p0[j];
      p1[j] = __expf(sc1[j] - m1); s1 += p1[j];
    }
#pragma unroll
    for (int off = 32; off; off >>= 1) {
      s0 += __shfl_xor(s0, off);
      s1 += __shfl_xor(s1, off);
    }
    if ((tx & 63) == 0) { redS[0][tx >> 6] = s0; redS[1][tx >> 6] = s1; }
  }
  __syncthreads();
  if (tx < 256) {
    const float s0 = (redS[0][0] + redS[0][1]) + (redS[0][2] + redS[0][3]);
    const float s1 = (redS[1][0] + redS[1][1]) + (redS[1][2] + redS[1][3]);
    const float r0 = 1.0f / s0;
    const float r1 = 1.0f / s1;
    float* arow0 = attn + (size_t)bt0 * SE + tx * 4;
    float* arow1 = arow0 + SE;
    *(float4*)arow0 = make_float4(p0[0] * r0, p0[1] * r0, p0[2] * r0, p0[3] * r0);
    *(float4*)arow1 = make_float4(p1[0] * r1, p1[1] * r1, p1[2] * r1, p1[3] * r1);
  }
}

// ---------------------------------------------------------------------------
// K3: partial context over s-chunks of 256. grid = sc(4) x tg(16) x b(4) = 256.
// WG: 8 t-rows x all 512 d; thread = 8t x 2d (16 fma per enc float2 load).
// attn tile (8x256 = 8 KB) staged in LDS, read as all-lane broadcasts.
__global__ __launch_bounds__(256, 1) void k_ctx_part(const float* __restrict__ attn,
                                                     const float* __restrict__ enc,
                                                     float* __restrict__ part) {
  __shared__ __align__(16) float at[8][256];
  const int wg = blockIdx.x;
  const int sch = wg & 3;
  const int tg = (wg >> 2) & 15;
  const int b = wg >> 6;
  const int tx = threadIdx.x;
  const int sbeg = sch * 256;
  {
    const int i = tx >> 5, c = (tx & 31) * 8;
    float4 v0 = *(const float4*)(attn + (size_t)(b * TD + tg * 8 + i) * SE + sbeg + c);
    float4 v1 = *(const float4*)(attn + (size_t)(b * TD + tg * 8 + i) * SE + sbeg + c + 4);
    *(float4*)&at[i][c] = v0;
    *(float4*)&at[i][c + 4] = v1;
  }
  __syncthreads();
  const int d0 = tx * 2;
  const float* ep = enc + ((size_t)b * SE + sbeg) * DD + d0;
  float2 acc[8] = {};
  for (int s = 0; s < 256; s += 4) {
    float4 av[8];
#pragma unroll
    for (int i = 0; i < 8; ++i) av[i] = *(const float4*)&at[i][s];
#pragma unroll
    for (int j = 0; j < 4; ++j) {
      const float2 ev = *(const float2*)(ep + (size_t)(s + j) * DD);
#pragma unroll
      for (int i = 0; i < 8; ++i) {
        const float aij = ((const float*)&av[i])[j];
        acc[i].x = fmaf(aij, ev.x, acc[i].x);
        acc[i].y = fmaf(aij, ev.y, acc[i].y);
      }
    }
  }
  float* pb = part + ((size_t)sch * (NB * TD) + b * TD + tg * 8) * DD + d0;
#pragma unroll
  for (int i = 0; i < 8; ++i)
    *(float2*)(pb + (size_t)i * DD) = acc[i];
}

// ---------------------------------------------------------------------------
// K4: ctx = sum of 4 partials. grid 256 x 256 thr, float4/thread.
__global__ __launch_bounds__(256, 1) void k_red(const float* __restrict__ part,
                                                float* __restrict__ ctx) {
  const size_t N = (size_t)NB * TD * DD;
  const size_t i = ((size_t)blockIdx.x * 256 + threadIdx.x) * 4;
  const float4 s0 = *(const float4*)(part + i);
  const float4 s1 = *(const float4*)(part + N + i);
  const float4 s2 = *(const float4*)(part + 2 * N + i);
  const float4 s3 = *(const float4*)(part + 3 * N + i);
  float4 o;
  o.x = (s0.x + s1.x) + (s2.x + s3.x);
  o.y = (s0.y + s1.y) + (s2.y + s3.y);
  o.z = (s0.z + s1.z) + (s2.z + s3.z);
  o.w = (s0.w + s1.w) + (s2.w + s3.w);
  *(float4*)(ctx + i) = o;
}

extern "C" void kernel_launch(void* const* d_in, const int* in_sizes, int n_in,
                              void* d_out, int out_size, void* d_ws, size_t ws_size,
                              hipStream_t stream) {
  const float* dec = (const float*)d_in[0];
  const float* enc = (const float*)d_in[1];
  const float* W1  = (const float*)d_in[2];
  const float* b1  = (const float*)d_in[3];
  const float* W2  = (const float*)d_in[4];
  const float* b2  = (const float*)d_in[5];
  const float* v   = (const float*)d_in[6];
  // d_in[7] = v_b: skipped — softmax is invariant to a uniform score shift.

  float* ctx  = (float*)d_out;                        // [4,128,512]
  float* attn = (float*)d_out + (size_t)NB * TD * DD; // [4,128,1024]

  float* ws    = (float*)d_ws;
  float* wencT = ws;                                  // [4][128][1024] 2 MB
  float* wdec  = wencT + (size_t)NB * UN * SE;        // [512][128] 256 KB
  float* part  = wdec + (size_t)NB * TD * UN;         // [4][512][512] 4 MB

  hipLaunchKernelGGL(k_proj, dim3(288), dim3(512), 0, stream,
                     enc, dec, W1, b1, W2, b2, wencT, wdec);
  hipLaunchKernelGGL(k_score, dim3(256), dim3(512), 0, stream,
                     wdec, v, wencT, attn);
  hipLaunchKernelGGL(k_ctx_part, dim3(256), dim3(256), 0, stream, attn, enc, part);
  hipLaunchKernelGGL(k_red, dim3(256), dim3(256), 0, stream, part, ctx);
}

// Round 6
// 111.506 us; speedup vs baseline: 1.1018x; 1.1018x over previous
//
#include <hip/hip_runtime.h>
#include <math.h>

#define NB 4      // batch
#define TD 128    // T_DEC
#define SE 1024   // S_ENC
#define DD 512    // D
#define UN 128    // UNITS

// tanh(x) = 1 - 2/(exp(2x)+1). exp via __expf (v_exp); rcp via v_rcp.
// Stable at +-inf; rel err ~1e-5 << 3e-3 tolerance.

// ---------------------------------------------------------------------------
// K1: projections — barrier-free, LDS-free, latency-tolerant.
// Grid 576 WGs x 256 thr: blk 0..511 -> enc rows (8/WG), 512..575 -> dec rows.
// Thread = (u = tx&127, rh = tx>>7): 4 rows x 1 u, full K=512.
//   - enc loads: wave-uniform float4 broadcasts (single L1 line per load)
//   - W loads:  lane-coalesced 256 B per wave per k (L2-hot, W1=256 KB)
//   - 4 independent FMA chains/thread; no __syncthreads anywhere.
// Output: enc rows -> wencT[b][u][s] (one float4 = 4 consecutive s);
//         dec rows -> wdec[row][u] (coalesced scalar stores).
__global__ __launch_bounds__(256, 4) void k_proj(const float* __restrict__ enc,
                                                 const float* __restrict__ dec,
                                                 const float* __restrict__ W1,
                                                 const float* __restrict__ b1,
                                                 const float* __restrict__ W2,
                                                 const float* __restrict__ b2,
                                                 float* __restrict__ wencT,
                                                 float* __restrict__ wdec) {
  const int tx = threadIdx.x;
  const int u = tx & 127;
  const int rh = tx >> 7;                 // 0/1
  const int blk = blockIdx.x;             // 0..575
  const bool is_enc = blk < 512;          // 512 enc WGs (4096 rows), 64 dec WGs (512 rows)
  const int row0 = blk * 8 + rh * 4;      // first of this thread's 4 rows (global numbering)
  const float* __restrict__ W = is_enc ? W1 : W2;
  const float* __restrict__ bias = is_enc ? b1 : b2;
  const float* __restrict__ src = is_enc
      ? (enc + (size_t)row0 * DD)
      : (dec + (size_t)(row0 - NB * SE) * DD);

  const float* wp = W + u;
  float acc0 = 0.f, acc1 = 0.f, acc2 = 0.f, acc3 = 0.f;

#pragma unroll 2
  for (int k0 = 0; k0 < DD; k0 += 4) {
    const float4 e0 = *(const float4*)(src + (size_t)0 * DD + k0);
    const float4 e1 = *(const float4*)(src + (size_t)1 * DD + k0);
    const float4 e2 = *(const float4*)(src + (size_t)2 * DD + k0);
    const float4 e3 = *(const float4*)(src + (size_t)3 * DD + k0);
#pragma unroll
    for (int kk = 0; kk < 4; ++kk) {
      const float w = wp[(size_t)(k0 + kk) * UN];
      acc0 = fmaf(((const float*)&e0)[kk], w, acc0);
      acc1 = fmaf(((const float*)&e1)[kk], w, acc1);
      acc2 = fmaf(((const float*)&e2)[kk], w, acc2);
      acc3 = fmaf(((const float*)&e3)[kk], w, acc3);
    }
  }

  const float bb = bias[u];
  if (is_enc) {
    const int b = row0 >> 10;             // row0 = b*1024 + s0
    const int s0 = row0 & 1023;
    float4 o = make_float4(acc0 + bb, acc1 + bb, acc2 + bb, acc3 + bb);
    *(float4*)(wencT + (size_t)(b * UN + u) * SE + s0) = o;
  } else {
    const int rb = row0 - NB * SE;
    wdec[(size_t)(rb + 0) * UN + u] = acc0 + bb;
    wdec[(size_t)(rb + 1) * UN + u] = acc1 + bb;
    wdec[(size_t)(rb + 2) * UN + u] = acc2 + bb;
    wdec[(size_t)(rb + 3) * UN + u] = acc3 + bb;
  }
}

// ---------------------------------------------------------------------------
// K2: scores + softmax. One WG (512 thr) per (b, t-pair): grid 256.
// Thread: 4 consecutive s (float4 coalesced stream over u) x 2 t x 64 u
// (u-half by wave group). wencT[b][u][s] stream is fully coalesced; wd/v are
// LDS broadcasts. v_b skipped (softmax shift-invariant).
__global__ __launch_bounds__(512, 1) void k_score(const float* __restrict__ wdec,
                                                  const float* __restrict__ v,
                                                  const float* __restrict__ wencT,
                                                  float* __restrict__ attn) {
  __shared__ __align__(16) float wd2[2][UN];        // 2*wdec row
  __shared__ __align__(16) float vsh[UN];
  __shared__ __align__(16) float parts[2][2][SE];   // [uhalf][tt][s]  16 KB
  __shared__ float redM[2][4], redS[2][4];

  const int wg = blockIdx.x;          // 0..255
  const int b = wg >> 6;
  const int t0 = (wg & 63) * 2;
  const int bt0 = b * TD + t0;
  const int tx = threadIdx.x;

  if (tx < 2 * UN) {
    const int tt = tx >> 7, u = tx & 127;
    wd2[tt][u] = 2.0f * wdec[(size_t)(bt0 + tt) * UN + u];
    if (tx < UN) vsh[tx] = v[tx];
  }
  __syncthreads();

  const int sq = tx & 255;            // s-quad 0..255
  const int uh = tx >> 8;             // u half 0/1
  const float* wp = wencT + (size_t)(b * UN + uh * 64) * SE + sq * 4;

  float a0[4] = {}, a1[4] = {};
  for (int ui = 0; ui < 64; ++ui) {
    const int u = uh * 64 + ui;
    const float4 w = *(const float4*)(wp + (size_t)ui * SE);
    const float vv = vsh[u];
    const float d0 = wd2[0][u];
    const float d1 = wd2[1][u];
#pragma unroll
    for (int j = 0; j < 4; ++j) {
      const float wj = ((const float*)&w)[j];
      float e0 = __expf(fmaf(wj, 2.0f, d0));
      float t0v = fmaf(-2.0f, __builtin_amdgcn_rcpf(e0 + 1.0f), 1.0f);
      a0[j] = fmaf(vv, t0v, a0[j]);
      float e1 = __expf(fmaf(wj, 2.0f, d1));
      float t1v = fmaf(-2.0f, __builtin_amdgcn_rcpf(e1 + 1.0f), 1.0f);
      a1[j] = fmaf(vv, t1v, a1[j]);
    }
  }
  *(float4*)&parts[uh][0][sq * 4] = make_float4(a0[0], a0[1], a0[2], a0[3]);
  *(float4*)&parts[uh][1][sq * 4] = make_float4(a1[0], a1[1], a1[2], a1[3]);
  __syncthreads();

  float sc0[4], sc1[4];
  if (tx < 256) {
    const float4 p00 = *(const float4*)&parts[0][0][tx * 4];
    const float4 p10 = *(const float4*)&parts[1][0][tx * 4];
    const float4 p01 = *(const float4*)&parts[0][1][tx * 4];
    const float4 p11 = *(const float4*)&parts[1][1][tx * 4];
    sc0[0] = p00.x + p10.x; sc0[1] = p00.y + p10.y;
    sc0[2] = p00.z + p10.z; sc0[3] = p00.w + p10.w;
    sc1[0] = p01.x + p11.x; sc1[1] = p01.y + p11.y;
    sc1[2] = p01.z + p11.z; sc1[3] = p01.w + p11.w;
    float m0 = fmaxf(fmaxf(sc0[0], sc0[1]), fmaxf(sc0[2], sc0[3]));
    float m1 = fmaxf(fmaxf(sc1[0], sc1[1]), fmaxf(sc1[2], sc1[3]));
#pragma unroll
    for (int off = 32; off; off >>= 1) {
      m0 = fmaxf(m0, __shfl_xor(m0, off));
      m1 = fmaxf(m1, __shfl_xor(m1, off));
    }
    if ((tx & 63) == 0) { redM[0][tx >> 6] = m0; redM[1][tx >> 6] = m1; }
  }
  __syncthreads();
  float p0[4], p1[4];
  if (tx < 256) {
    const float m0 = fmaxf(fmaxf(redM[0][0], redM[0][1]), fmaxf(redM[0][2], redM[0][3]));
    const float m1 = fmaxf(fmaxf(redM[1][0], redM[1][1]), fmaxf(redM[1][2], redM[1][3]));
    float s0 = 0.f, s1 = 0.f;
#pragma unroll
    for (int j = 0; j < 4; ++j) {
      p0[j] = __expf(sc0[j] - m0); s0 += p0[j];
      p1[j] = __expf(sc1[j] - m1); s1 += p1[j];
    }
#pragma unroll
    for (int off = 32; off; off >>= 1) {
      s0 += __shfl_xor(s0, off);
      s1 += __shfl_xor(s1, off);
    }
    if ((tx & 63) == 0) { redS[0][tx >> 6] = s0; redS[1][tx >> 6] = s1; }
  }
  __syncthreads();
  if (tx < 256) {
    const float s0 = (redS[0][0] + redS[0][1]) + (redS[0][2] + redS[0][3]);
    const float s1 = (redS[1][0] + redS[1][1]) + (redS[1][2] + redS[1][3]);
    const float r0 = 1.0f / s0;
    const float r1 = 1.0f / s1;
    float* arow0 = attn + (size_t)bt0 * SE + tx * 4;
    float* arow1 = arow0 + SE;
    *(float4*)arow0 = make_float4(p0[0] * r0, p0[1] * r0, p0[2] * r0, p0[3] * r0);
    *(float4*)arow1 = make_float4(p1[0] * r1, p1[1] * r1, p1[2] * r1, p1[3] * r1);
  }
}

// ---------------------------------------------------------------------------
// K3: partial context over s-chunks of 256. grid = sc(4) x tg(16) x b(4) = 256.
// WG: 8 t-rows x all 512 d; thread = 8t x 2d (16 fma per enc float2 load).
// attn tile (8x256 = 8 KB) staged in LDS, read as all-lane broadcasts.
__global__ __launch_bounds__(256, 1) void k_ctx_part(const float* __restrict__ attn,
                                                     const float* __restrict__ enc,
                                                     float* __restrict__ part) {
  __shared__ __align__(16) float at[8][256];
  const int wg = blockIdx.x;
  const int sch = wg & 3;
  const int tg = (wg >> 2) & 15;
  const int b = wg >> 6;
  const int tx = threadIdx.x;
  const int sbeg = sch * 256;
  {
    const int i = tx >> 5, c = (tx & 31) * 8;
    float4 v0 = *(const float4*)(attn + (size_t)(b * TD + tg * 8 + i) * SE + sbeg + c);
    float4 v1 = *(const float4*)(attn + (size_t)(b * TD + tg * 8 + i) * SE + sbeg + c + 4);
    *(float4*)&at[i][c] = v0;
    *(float4*)&at[i][c + 4] = v1;
  }
  __syncthreads();
  const int d0 = tx * 2;
  const float* ep = enc + ((size_t)b * SE + sbeg) * DD + d0;
  float2 acc[8] = {};
  for (int s = 0; s < 256; s += 4) {
    float4 av[8];
#pragma unroll
    for (int i = 0; i < 8; ++i) av[i] = *(const float4*)&at[i][s];
#pragma unroll
    for (int j = 0; j < 4; ++j) {
      const float2 ev = *(const float2*)(ep + (size_t)(s + j) * DD);
#pragma unroll
      for (int i = 0; i < 8; ++i) {
        const float aij = ((const float*)&av[i])[j];
        acc[i].x = fmaf(aij, ev.x, acc[i].x);
        acc[i].y = fmaf(aij, ev.y, acc[i].y);
      }
    }
  }
  float* pb = part + ((size_t)sch * (NB * TD) + b * TD + tg * 8) * DD + d0;
#pragma unroll
  for (int i = 0; i < 8; ++i)
    *(float2*)(pb + (size_t)i * DD) = acc[i];
}

// ---------------------------------------------------------------------------
// K4: ctx = sum of 4 partials. grid 256 x 256 thr, float4/thread.
__global__ __launch_bounds__(256, 1) void k_red(const float* __restrict__ part,
                                                float* __restrict__ ctx) {
  const size_t N = (size_t)NB * TD * DD;
  const size_t i = ((size_t)blockIdx.x * 256 + threadIdx.x) * 4;
  const float4 s0 = *(const float4*)(part + i);
  const float4 s1 = *(const float4*)(part + N + i);
  const float4 s2 = *(const float4*)(part + 2 * N + i);
  const float4 s3 = *(const float4*)(part + 3 * N + i);
  float4 o;
  o.x = (s0.x + s1.x) + (s2.x + s3.x);
  o.y = (s0.y + s1.y) + (s2.y + s3.y);
  o.z = (s0.z + s1.z) + (s2.z + s3.z);
  o.w = (s0.w + s1.w) + (s2.w + s3.w);
  *(float4*)(ctx + i) = o;
}

extern "C" void kernel_launch(void* const* d_in, const int* in_sizes, int n_in,
                              void* d_out, int out_size, void* d_ws, size_t ws_size,
                              hipStream_t stream) {
  const float* dec = (const float*)d_in[0];
  const float* enc = (const float*)d_in[1];
  const float* W1  = (const float*)d_in[2];
  const float* b1  = (const float*)d_in[3];
  const float* W2  = (const float*)d_in[4];
  const float* b2  = (const float*)d_in[5];
  const float* v   = (const float*)d_in[6];
  // d_in[7] = v_b: skipped — softmax is invariant to a uniform score shift.

  float* ctx  = (float*)d_out;                        // [4,128,512]
  float* attn = (float*)d_out + (size_t)NB * TD * DD; // [4,128,1024]

  float* ws    = (float*)d_ws;
  float* wencT = ws;                                  // [4][128][1024] 2 MB
  float* wdec  = wencT + (size_t)NB * UN * SE;        // [512][128] 256 KB
  float* part  = wdec + (size_t)NB * TD * UN;         // [4][512][512] 4 MB

  hipLaunchKernelGGL(k_proj, dim3(576), dim3(256), 0, stream,
                     enc, dec, W1, b1, W2, b2, wencT, wdec);
  hipLaunchKernelGGL(k_score, dim3(256), dim3(512), 0, stream,
                     wdec, v, wencT, attn);
  hipLaunchKernelGGL(k_ctx_part, dim3(256), dim3(256), 0, stream, attn, enc, part);
  hipLaunchKernelGGL(k_red, dim3(256), dim3(256), 0, stream, part, ctx);
}

// Round 7
// 102.731 us; speedup vs baseline: 1.1960x; 1.0854x over previous
//
#include <hip/hip_runtime.h>
#include <math.h>

#define NB 4      // batch
#define TD 128    // T_DEC
#define SE 1024   // S_ENC
#define DD 512    // D
#define UN 128    // UNITS

// tanh(x) = 1 - 2/(exp(2x)+1). exp via __expf (v_exp); rcp via v_rcp.
// Stable at +-inf; rel err ~1e-5 << 3e-3 tolerance.

// ---------------------------------------------------------------------------
// K1: projections — k_ctx_part-style: A rows staged in LDS (broadcast reads),
// W streamed from global with per-lane coalesced float2 loads.
// Grid 576 x 256 thr: blk 0..511 -> 8 enc rows each; 512..575 -> 8 dec rows.
// Thread = (u2 = (tx&63)*2, wave rq = tx>>6 -> rows rq*2, rq*2+1).
// One LDS stage (16 KB contiguous copy) + single barrier; inner K-loop has
// zero barriers: 2 ds_read_b128 (wave-uniform broadcast) + 4 coalesced W
// float2 loads + 16 FMA per k-quad, 4 independent acc chains.
__global__ __launch_bounds__(256, 4) void k_proj(const float* __restrict__ enc,
                                                 const float* __restrict__ dec,
                                                 const float* __restrict__ W1,
                                                 const float* __restrict__ b1,
                                                 const float* __restrict__ W2,
                                                 const float* __restrict__ b2,
                                                 float* __restrict__ wencT,
                                                 float* __restrict__ wdec) {
  __shared__ __align__(16) float At[8 * DD];   // 16 KB: 8 rows x 512 k

  const int tx = threadIdx.x;
  const int blk = blockIdx.x;
  const bool is_enc = blk < 512;
  const int row_base = is_enc ? blk * 8 : (blk - 512) * 8;
  const float* __restrict__ src = (is_enc ? enc : dec) + (size_t)row_base * DD;
  const float* __restrict__ W = is_enc ? W1 : W2;
  const float* __restrict__ bias = is_enc ? b1 : b2;

  // Stage: 8 consecutive rows are 4096 contiguous floats -> straight copy.
#pragma unroll
  for (int i = 0; i < 4; ++i) {
    const int idx = (i * 256 + tx) * 4;
    *(float4*)&At[idx] = *(const float4*)(src + idx);
  }
  __syncthreads();

  const int u2 = (tx & 63) * 2;
  const int r0 = (tx >> 6) * 2;          // wave-uniform row pair
  const float* __restrict__ Wp = W + u2;

  float acc00 = 0.f, acc01 = 0.f, acc10 = 0.f, acc11 = 0.f;
#pragma unroll 2
  for (int k = 0; k < DD; k += 4) {
    const float4 a0 = *(const float4*)&At[(r0 + 0) * DD + k];
    const float4 a1 = *(const float4*)&At[(r0 + 1) * DD + k];
#pragma unroll
    for (int j = 0; j < 4; ++j) {
      const float2 w = *(const float2*)(Wp + (size_t)(k + j) * UN);
      const float a0j = ((const float*)&a0)[j];
      const float a1j = ((const float*)&a1)[j];
      acc00 = fmaf(a0j, w.x, acc00);
      acc01 = fmaf(a0j, w.y, acc01);
      acc10 = fmaf(a1j, w.x, acc10);
      acc11 = fmaf(a1j, w.y, acc11);
    }
  }

  const float bb0 = bias[u2];
  const float bb1 = bias[u2 + 1];
  if (is_enc) {
    const int b = row_base >> 10;
    const int s0 = (row_base & 1023) + r0;   // this thread's two s values: s0, s0+1
    *(float2*)(wencT + ((size_t)(b * UN + u2)) * SE + s0) =
        make_float2(acc00 + bb0, acc10 + bb0);
    *(float2*)(wencT + ((size_t)(b * UN + u2 + 1)) * SE + s0) =
        make_float2(acc01 + bb1, acc11 + bb1);
  } else {
    const int rb = row_base + r0;
    *(float2*)(wdec + (size_t)(rb + 0) * UN + u2) = make_float2(acc00 + bb0, acc01 + bb1);
    *(float2*)(wdec + (size_t)(rb + 1) * UN + u2) = make_float2(acc10 + bb0, acc11 + bb1);
  }
}

// ---------------------------------------------------------------------------
// K2: scores + softmax. One WG (512 thr) per (b, t-pair): grid 256.
// Thread: 4 consecutive s (float4 coalesced stream over u) x 2 t x 64 u
// (u-half by wave group). wencT[b][u][s] stream is fully coalesced; wd/v are
// LDS broadcasts. v_b skipped (softmax shift-invariant).
__global__ __launch_bounds__(512, 1) void k_score(const float* __restrict__ wdec,
                                                  const float* __restrict__ v,
                                                  const float* __restrict__ wencT,
                                                  float* __restrict__ attn) {
  __shared__ __align__(16) float wd2[2][UN];        // 2*wdec row
  __shared__ __align__(16) float vsh[UN];
  __shared__ __align__(16) float parts[2][2][SE];   // [uhalf][tt][s]  16 KB
  __shared__ float redM[2][4], redS[2][4];

  const int wg = blockIdx.x;          // 0..255
  const int b = wg >> 6;
  const int t0 = (wg & 63) * 2;
  const int bt0 = b * TD + t0;
  const int tx = threadIdx.x;

  if (tx < 2 * UN) {
    const int tt = tx >> 7, u = tx & 127;
    wd2[tt][u] = 2.0f * wdec[(size_t)(bt0 + tt) * UN + u];
    if (tx < UN) vsh[tx] = v[tx];
  }
  __syncthreads();

  const int sq = tx & 255;            // s-quad 0..255
  const int uh = tx >> 8;             // u half 0/1
  const float* wp = wencT + (size_t)(b * UN + uh * 64) * SE + sq * 4;

  float a0[4] = {}, a1[4] = {};
  for (int ui = 0; ui < 64; ++ui) {
    const int u = uh * 64 + ui;
    const float4 w = *(const float4*)(wp + (size_t)ui * SE);
    const float vv = vsh[u];
    const float d0 = wd2[0][u];
    const float d1 = wd2[1][u];
#pragma unroll
    for (int j = 0; j < 4; ++j) {
      const float wj = ((const float*)&w)[j];
      float e0 = __expf(fmaf(wj, 2.0f, d0));
      float t0v = fmaf(-2.0f, __builtin_amdgcn_rcpf(e0 + 1.0f), 1.0f);
      a0[j] = fmaf(vv, t0v, a0[j]);
      float e1 = __expf(fmaf(wj, 2.0f, d1));
      float t1v = fmaf(-2.0f, __builtin_amdgcn_rcpf(e1 + 1.0f), 1.0f);
      a1[j] = fmaf(vv, t1v, a1[j]);
    }
  }
  *(float4*)&parts[uh][0][sq * 4] = make_float4(a0[0], a0[1], a0[2], a0[3]);
  *(float4*)&parts[uh][1][sq * 4] = make_float4(a1[0], a1[1], a1[2], a1[3]);
  __syncthreads();

  float sc0[4], sc1[4];
  if (tx < 256) {
    const float4 p00 = *(const float4*)&parts[0][0][tx * 4];
    const float4 p10 = *(const float4*)&parts[1][0][tx * 4];
    const float4 p01 = *(const float4*)&parts[0][1][tx * 4];
    const float4 p11 = *(const float4*)&parts[1][1][tx * 4];
    sc0[0] = p00.x + p10.x; sc0[1] = p00.y + p10.y;
    sc0[2] = p00.z + p10.z; sc0[3] = p00.w + p10.w;
    sc1[0] = p01.x + p11.x; sc1[1] = p01.y + p11.y;
    sc1[2] = p01.z + p11.z; sc1[3] = p01.w + p11.w;
    float m0 = fmaxf(fmaxf(sc0[0], sc0[1]), fmaxf(sc0[2], sc0[3]));
    float m1 = fmaxf(fmaxf(sc1[0], sc1[1]), fmaxf(sc1[2], sc1[3]));
#pragma unroll
    for (int off = 32; off; off >>= 1) {
      m0 = fmaxf(m0, __shfl_xor(m0, off));
      m1 = fmaxf(m1, __shfl_xor(m1, off));
    }
    if ((tx & 63) == 0) { redM[0][tx >> 6] = m0; redM[1][tx >> 6] = m1; }
  }
  __syncthreads();
  float p0[4], p1[4];
  if (tx < 256) {
    const float m0 = fmaxf(fmaxf(redM[0][0], redM[0][1]), fmaxf(redM[0][2], redM[0][3]));
    const float m1 = fmaxf(fmaxf(redM[1][0], redM[1][1]), fmaxf(redM[1][2], redM[1][3]));
    float s0 = 0.f, s1 = 0.f;
#pragma unroll
    for (int j = 0; j < 4; ++j) {
      p0[j] = __expf(sc0[j] - m0); s0 += p0[j];
      p1[j] = __expf(sc1[j] - m1); s1 += p1[j];
    }
#pragma unroll
    for (int off = 32; off; off >>= 1) {
      s0 += __shfl_xor(s0, off);
      s1 += __shfl_xor(s1, off);
    }
    if ((tx & 63) == 0) { redS[0][tx >> 6] = s0; redS[1][tx >> 6] = s1; }
  }
  __syncthreads();
  if (tx < 256) {
    const float s0 = (redS[0][0] + redS[0][1]) + (redS[0][2] + redS[0][3]);
    const float s1 = (redS[1][0] + redS[1][1]) + (redS[1][2] + redS[1][3]);
    const float r0 = 1.0f / s0;
    const float r1 = 1.0f / s1;
    float* arow0 = attn + (size_t)bt0 * SE + tx * 4;
    float* arow1 = arow0 + SE;
    *(float4*)arow0 = make_float4(p0[0] * r0, p0[1] * r0, p0[2] * r0, p0[3] * r0);
    *(float4*)arow1 = make_float4(p1[0] * r1, p1[1] * r1, p1[2] * r1, p1[3] * r1);
  }
}

// ---------------------------------------------------------------------------
// K3: partial context over s-chunks of 256. grid = sc(4) x tg(16) x b(4) = 256.
// WG: 8 t-rows x all 512 d; thread = 8t x 2d (16 fma per enc float2 load).
// attn tile (8x256 = 8 KB) staged in LDS, read as all-lane broadcasts.
__global__ __launch_bounds__(256, 1) void k_ctx_part(const float* __restrict__ attn,
                                                     const float* __restrict__ enc,
                                                     float* __restrict__ part) {
  __shared__ __align__(16) float at[8][256];
  const int wg = blockIdx.x;
  const int sch = wg & 3;
  const int tg = (wg >> 2) & 15;
  const int b = wg >> 6;
  const int tx = threadIdx.x;
  const int sbeg = sch * 256;
  {
    const int i = tx >> 5, c = (tx & 31) * 8;
    float4 v0 = *(const float4*)(attn + (size_t)(b * TD + tg * 8 + i) * SE + sbeg + c);
    float4 v1 = *(const float4*)(attn + (size_t)(b * TD + tg * 8 + i) * SE + sbeg + c + 4);
    *(float4*)&at[i][c] = v0;
    *(float4*)&at[i][c + 4] = v1;
  }
  __syncthreads();
  const int d0 = tx * 2;
  const float* ep = enc + ((size_t)b * SE + sbeg) * DD + d0;
  float2 acc[8] = {};
  for (int s = 0; s < 256; s += 4) {
    float4 av[8];
#pragma unroll
    for (int i = 0; i < 8; ++i) av[i] = *(const float4*)&at[i][s];
#pragma unroll
    for (int j = 0; j < 4; ++j) {
      const float2 ev = *(const float2*)(ep + (size_t)(s + j) * DD);
#pragma unroll
      for (int i = 0; i < 8; ++i) {
        const float aij = ((const float*)&av[i])[j];
        acc[i].x = fmaf(aij, ev.x, acc[i].x);
        acc[i].y = fmaf(aij, ev.y, acc[i].y);
      }
    }
  }
  float* pb = part + ((size_t)sch * (NB * TD) + b * TD + tg * 8) * DD + d0;
#pragma unroll
  for (int i = 0; i < 8; ++i)
    *(float2*)(pb + (size_t)i * DD) = acc[i];
}

// ---------------------------------------------------------------------------
// K4: ctx = sum of 4 partials. grid 256 x 256 thr, float4/thread.
__global__ __launch_bounds__(256, 1) void k_red(const float* __restrict__ part,
                                                float* __restrict__ ctx) {
  const size_t N = (size_t)NB * TD * DD;
  const size_t i = ((size_t)blockIdx.x * 256 + threadIdx.x) * 4;
  const float4 s0 = *(const float4*)(part + i);
  const float4 s1 = *(const float4*)(part + N + i);
  const float4 s2 = *(const float4*)(part + 2 * N + i);
  const float4 s3 = *(const float4*)(part + 3 * N + i);
  float4 o;
  o.x = (s0.x + s1.x) + (s2.x + s3.x);
  o.y = (s0.y + s1.y) + (s2.y + s3.y);
  o.z = (s0.z + s1.z) + (s2.z + s3.z);
  o.w = (s0.w + s1.w) + (s2.w + s3.w);
  *(float4*)(ctx + i) = o;
}

extern "C" void kernel_launch(void* const* d_in, const int* in_sizes, int n_in,
                              void* d_out, int out_size, void* d_ws, size_t ws_size,
                              hipStream_t stream) {
  const float* dec = (const float*)d_in[0];
  const float* enc = (const float*)d_in[1];
  const float* W1  = (const float*)d_in[2];
  const float* b1  = (const float*)d_in[3];
  const float* W2  = (const float*)d_in[4];
  const float* b2  = (const float*)d_in[5];
  const float* v   = (const float*)d_in[6];
  // d_in[7] = v_b: skipped — softmax is invariant to a uniform score shift.

  float* ctx  = (float*)d_out;                        // [4,128,512]
  float* attn = (float*)d_out + (size_t)NB * TD * DD; // [4,128,1024]

  float* ws    = (float*)d_ws;
  float* wencT = ws;                                  // [4][128][1024] 2 MB
  float* wdec  = wencT + (size_t)NB * UN * SE;        // [512][128] 256 KB
  float* part  = wdec + (size_t)NB * TD * UN;         // [4][512][512] 4 MB

  hipLaunchKernelGGL(k_proj, dim3(576), dim3(256), 0, stream,
                     enc, dec, W1, b1, W2, b2, wencT, wdec);
  hipLaunchKernelGGL(k_score, dim3(256), dim3(512), 0, stream,
                     wdec, v, wencT, attn);
  hipLaunchKernelGGL(k_ctx_part, dim3(256), dim3(256), 0, stream, attn, enc, part);
  hipLaunchKernelGGL(k_red, dim3(256), dim3(256), 0, stream, part, ctx);
}

// Round 8
// 79.504 us; speedup vs baseline: 1.5454x; 1.2921x over previous
//
#include <hip/hip_runtime.h>
#include <math.h>

#define NB 4      // batch
#define TD 128    // T_DEC
#define SE 1024   // S_ENC
#define DD 512    // D
#define UN 128    // UNITS
#define NROWS 4608          // 4096 enc + 512 dec
#define KSPLIT 4

// tanh(x) = 1 - 2/(exp(2x)+1). exp via __expf (v_exp); rcp via v_rcp.
// Stable at +-inf; rel err ~1e-5 << 3e-3 tolerance.

// ---------------------------------------------------------------------------
// K1a: projection partials. grid (288, 4): blockIdx.x = row-block (16 rows),
// blockIdx.y = ks (K slice of 128). blk 0..255 -> enc rows, 256..287 -> dec.
// Stage 16 rows x 128 k (8 KB) in LDS; thread = (u2 = (tx&63)*2, wave ->
// rows (tx>>6)*4 .. +3). Per k: 1 coalesced float2 W load + 8 FMA
// (8 independent chains). 1152 WGs = 18 waves/CU.
__global__ __launch_bounds__(256, 4) void k_proj_part(const float* __restrict__ enc,
                                                      const float* __restrict__ dec,
                                                      const float* __restrict__ W1,
                                                      const float* __restrict__ W2,
                                                      float* __restrict__ part) {
  __shared__ __align__(16) float At[16 * 128];   // 8 KB

  const int tx = threadIdx.x;
  const int rb = blockIdx.x;            // 0..287
  const int ks = blockIdx.y;            // 0..3
  const bool is_enc = rb < 256;
  const int row_base = rb * 16;         // global row numbering 0..4607
  const float* __restrict__ src = is_enc
      ? (enc + (size_t)row_base * DD)
      : (dec + (size_t)(row_base - NB * SE) * DD);
  const float* __restrict__ W = is_enc ? W1 : W2;
  const int kb = ks * 128;

  // stage: 16 rows x 128 k = 512 float4, 2 per thread, 128B coalesced runs
#pragma unroll
  for (int i = 0; i < 2; ++i) {
    const int idx = i * 256 + tx;       // 0..511
    const int row = idx >> 5;           // 32 float4 per row
    const int c4 = (idx & 31) * 4;
    *(float4*)&At[row * 128 + c4] = *(const float4*)(src + (size_t)row * DD + kb + c4);
  }
  __syncthreads();

  const int u2 = (tx & 63) * 2;
  const int r0 = (tx >> 6) * 4;         // wave-uniform row group
  const float* __restrict__ Wp = W + (size_t)kb * UN + u2;

  float acc[4][2] = {};
#pragma unroll 2
  for (int k = 0; k < 128; k += 4) {
    float4 a[4];
#pragma unroll
    for (int r = 0; r < 4; ++r)
      a[r] = *(const float4*)&At[(r0 + r) * 128 + k];   // wave-uniform broadcast
#pragma unroll
    for (int j = 0; j < 4; ++j) {
      const float2 w = *(const float2*)(Wp + (size_t)(k + j) * UN);
#pragma unroll
      for (int r = 0; r < 4; ++r) {
        const float arj = ((const float*)&a[r])[j];
        acc[r][0] = fmaf(arj, w.x, acc[r][0]);
        acc[r][1] = fmaf(arj, w.y, acc[r][1]);
      }
    }
  }

  float* pb = part + ((size_t)ks * NROWS + row_base + r0) * UN + u2;
#pragma unroll
  for (int r = 0; r < 4; ++r)
    *(float2*)(pb + (size_t)r * UN) = make_float2(acc[r][0], acc[r][1]);
}

// ---------------------------------------------------------------------------
// K1b: reduce 4 K-partials + bias; enc rows -> wencT (transposed via LDS),
// dec rows -> wdec. grid 288 x 256 thr; thread sums 8 u of one row.
__global__ __launch_bounds__(256, 4) void k_redT(const float* __restrict__ part,
                                                 const float* __restrict__ b1,
                                                 const float* __restrict__ b2,
                                                 float* __restrict__ wencT,
                                                 float* __restrict__ wdec) {
  __shared__ __align__(16) float Tt[16][132];
  const int tx = threadIdx.x;
  const int rb = blockIdx.x;
  const int row_base = rb * 16;
  const bool is_enc = rb < 256;
  const int r = tx >> 4;                // 0..15
  const int u0 = (tx & 15) * 8;         // 8 u per thread
  const size_t N = (size_t)NROWS * UN;

  const float* p = part + (size_t)(row_base + r) * UN + u0;
  float4 sa = *(const float4*)(p);
  float4 sb = *(const float4*)(p + 4);
#pragma unroll
  for (int s = 1; s < KSPLIT; ++s) {
    const float4 qa = *(const float4*)(p + (size_t)s * N);
    const float4 qb = *(const float4*)(p + (size_t)s * N + 4);
    sa.x += qa.x; sa.y += qa.y; sa.z += qa.z; sa.w += qa.w;
    sb.x += qb.x; sb.y += qb.y; sb.z += qb.z; sb.w += qb.w;
  }
  const float* bias = is_enc ? b1 : b2;
  const float4 ba = *(const float4*)(bias + u0);
  const float4 bb = *(const float4*)(bias + u0 + 4);
  sa.x += ba.x; sa.y += ba.y; sa.z += ba.z; sa.w += ba.w;
  sb.x += bb.x; sb.y += bb.y; sb.z += bb.z; sb.w += bb.w;

  if (is_enc) {
    *(float4*)&Tt[r][u0] = sa;
    *(float4*)&Tt[r][u0 + 4] = sb;
    __syncthreads();
    const int b = row_base >> 10;
    const int s0 = row_base & 1023;
    const int u = tx >> 1;
    const int sh = tx & 1;
    float o[8];
#pragma unroll
    for (int j = 0; j < 8; ++j) o[j] = Tt[sh * 8 + j][u];
    float* dst = wencT + (size_t)(b * UN + u) * SE + s0 + sh * 8;
    *(float4*)dst = make_float4(o[0], o[1], o[2], o[3]);
    *(float4*)(dst + 4) = make_float4(o[4], o[5], o[6], o[7]);
  } else {
    float* dst = wdec + (size_t)(row_base - NB * SE + r) * UN + u0;
    *(float4*)dst = sa;
    *(float4*)(dst + 4) = sb;
  }
}

// ---------------------------------------------------------------------------
// K2: scores + softmax. One WG (512 thr) per (b, t-pair): grid 256.
// Thread: 4 consecutive s (float4 coalesced stream over u) x 2 t x 64 u
// (u-half by wave group). wencT[b][u][s] stream is fully coalesced; wd/v are
// LDS broadcasts. v_b skipped (softmax shift-invariant).
__global__ __launch_bounds__(512, 1) void k_score(const float* __restrict__ wdec,
                                                  const float* __restrict__ v,
                                                  const float* __restrict__ wencT,
                                                  float* __restrict__ attn) {
  __shared__ __align__(16) float wd2[2][UN];        // 2*wdec row
  __shared__ __align__(16) float vsh[UN];
  __shared__ __align__(16) float parts[2][2][SE];   // [uhalf][tt][s]  16 KB
  __shared__ float redM[2][4], redS[2][4];

  const int wg = blockIdx.x;          // 0..255
  const int b = wg >> 6;
  const int t0 = (wg & 63) * 2;
  const int bt0 = b * TD + t0;
  const int tx = threadIdx.x;

  if (tx < 2 * UN) {
    const int tt = tx >> 7, u = tx & 127;
    wd2[tt][u] = 2.0f * wdec[(size_t)(bt0 + tt) * UN + u];
    if (tx < UN) vsh[tx] = v[tx];
  }
  __syncthreads();

  const int sq = tx & 255;            // s-quad 0..255
  const int uh = tx >> 8;             // u half 0/1
  const float* wp = wencT + (size_t)(b * UN + uh * 64) * SE + sq * 4;

  float a0[4] = {}, a1[4] = {};
  for (int ui = 0; ui < 64; ++ui) {
    const int u = uh * 64 + ui;
    const float4 w = *(const float4*)(wp + (size_t)ui * SE);
    const float vv = vsh[u];
    const float d0 = wd2[0][u];
    const float d1 = wd2[1][u];
#pragma unroll
    for (int j = 0; j < 4; ++j) {
      const float wj = ((const float*)&w)[j];
      float e0 = __expf(fmaf(wj, 2.0f, d0));
      float t0v = fmaf(-2.0f, __builtin_amdgcn_rcpf(e0 + 1.0f), 1.0f);
      a0[j] = fmaf(vv, t0v, a0[j]);
      float e1 = __expf(fmaf(wj, 2.0f, d1));
      float t1v = fmaf(-2.0f, __builtin_amdgcn_rcpf(e1 + 1.0f), 1.0f);
      a1[j] = fmaf(vv, t1v, a1[j]);
    }
  }
  *(float4*)&parts[uh][0][sq * 4] = make_float4(a0[0], a0[1], a0[2], a0[3]);
  *(float4*)&parts[uh][1][sq * 4] = make_float4(a1[0], a1[1], a1[2], a1[3]);
  __syncthreads();

  float sc0[4], sc1[4];
  if (tx < 256) {
    const float4 p00 = *(const float4*)&parts[0][0][tx * 4];
    const float4 p10 = *(const float4*)&parts[1][0][tx * 4];
    const float4 p01 = *(const float4*)&parts[0][1][tx * 4];
    const float4 p11 = *(const float4*)&parts[1][1][tx * 4];
    sc0[0] = p00.x + p10.x; sc0[1] = p00.y + p10.y;
    sc0[2] = p00.z + p10.z; sc0[3] = p00.w + p10.w;
    sc1[0] = p01.x + p11.x; sc1[1] = p01.y + p11.y;
    sc1[2] = p01.z + p11.z; sc1[3] = p01.w + p11.w;
    float m0 = fmaxf(fmaxf(sc0[0], sc0[1]), fmaxf(sc0[2], sc0[3]));
    float m1 = fmaxf(fmaxf(sc1[0], sc1[1]), fmaxf(sc1[2], sc1[3]));
#pragma unroll
    for (int off = 32; off; off >>= 1) {
      m0 = fmaxf(m0, __shfl_xor(m0, off));
      m1 = fmaxf(m1, __shfl_xor(m1, off));
    }
    if ((tx & 63) == 0) { redM[0][tx >> 6] = m0; redM[1][tx >> 6] = m1; }
  }
  __syncthreads();
  float p0[4], p1[4];
  if (tx < 256) {
    const float m0 = fmaxf(fmaxf(redM[0][0], redM[0][1]), fmaxf(redM[0][2], redM[0][3]));
    const float m1 = fmaxf(fmaxf(redM[1][0], redM[1][1]), fmaxf(redM[1][2], redM[1][3]));
    float s0 = 0.f, s1 = 0.f;
#pragma unroll
    for (int j = 0; j < 4; ++j) {
      p0[j] = __expf(sc0[j] - m0); s0 += p0[j];
      p1[j] = __expf(sc1[j] - m1); s1 += p1[j];
    }
#pragma unroll
    for (int off = 32; off; off >>= 1) {
      s0 += __shfl_xor(s0, off);
      s1 += __shfl_xor(s1, off);
    }
    if ((tx & 63) == 0) { redS[0][tx >> 6] = s0; redS[1][tx >> 6] = s1; }
  }
  __syncthreads();
  if (tx < 256) {
    const float s0 = (redS[0][0] + redS[0][1]) + (redS[0][2] + redS[0][3]);
    const float s1 = (redS[1][0] + redS[1][1]) + (redS[1][2] + redS[1][3]);
    const float r0 = 1.0f / s0;
    const float r1 = 1.0f / s1;
    float* arow0 = attn + (size_t)bt0 * SE + tx * 4;
    float* arow1 = arow0 + SE;
    *(float4*)arow0 = make_float4(p0[0] * r0, p0[1] * r0, p0[2] * r0, p0[3] * r0);
    *(float4*)arow1 = make_float4(p1[0] * r1, p1[1] * r1, p1[2] * r1, p1[3] * r1);
  }
}

// ---------------------------------------------------------------------------
// K3: partial context over s-chunks of 256. grid = sc(4) x tg(16) x b(4) = 256.
// WG: 8 t-rows x all 512 d; thread = 8t x 2d (16 fma per enc float2 load).
// attn tile (8x256 = 8 KB) staged in LDS, read as all-lane broadcasts.
__global__ __launch_bounds__(256, 1) void k_ctx_part(const float* __restrict__ attn,
                                                     const float* __restrict__ enc,
                                                     float* __restrict__ part) {
  __shared__ __align__(16) float at[8][256];
  const int wg = blockIdx.x;
  const int sch = wg & 3;
  const int tg = (wg >> 2) & 15;
  const int b = wg >> 6;
  const int tx = threadIdx.x;
  const int sbeg = sch * 256;
  {
    const int i = tx >> 5, c = (tx & 31) * 8;
    float4 v0 = *(const float4*)(attn + (size_t)(b * TD + tg * 8 + i) * SE + sbeg + c);
    float4 v1 = *(const float4*)(attn + (size_t)(b * TD + tg * 8 + i) * SE + sbeg + c + 4);
    *(float4*)&at[i][c] = v0;
    *(float4*)&at[i][c + 4] = v1;
  }
  __syncthreads();
  const int d0 = tx * 2;
  const float* ep = enc + ((size_t)b * SE + sbeg) * DD + d0;
  float2 acc[8] = {};
  for (int s = 0; s < 256; s += 4) {
    float4 av[8];
#pragma unroll
    for (int i = 0; i < 8; ++i) av[i] = *(const float4*)&at[i][s];
#pragma unroll
    for (int j = 0; j < 4; ++j) {
      const float2 ev = *(const float2*)(ep + (size_t)(s + j) * DD);
#pragma unroll
      for (int i = 0; i < 8; ++i) {
        const float aij = ((const float*)&av[i])[j];
        acc[i].x = fmaf(aij, ev.x, acc[i].x);
        acc[i].y = fmaf(aij, ev.y, acc[i].y);
      }
    }
  }
  float* pb = part + ((size_t)sch * (NB * TD) + b * TD + tg * 8) * DD + d0;
#pragma unroll
  for (int i = 0; i < 8; ++i)
    *(float2*)(pb + (size_t)i * DD) = acc[i];
}

// ---------------------------------------------------------------------------
// K4: ctx = sum of 4 partials. grid 256 x 256 thr, float4/thread.
__global__ __launch_bounds__(256, 1) void k_red(const float* __restrict__ part,
                                                float* __restrict__ ctx) {
  const size_t N = (size_t)NB * TD * DD;
  const size_t i = ((size_t)blockIdx.x * 256 + threadIdx.x) * 4;
  const float4 s0 = *(const float4*)(part + i);
  const float4 s1 = *(const float4*)(part + N + i);
  const float4 s2 = *(const float4*)(part + 2 * N + i);
  const float4 s3 = *(const float4*)(part + 3 * N + i);
  float4 o;
  o.x = (s0.x + s1.x) + (s2.x + s3.x);
  o.y = (s0.y + s1.y) + (s2.y + s3.y);
  o.z = (s0.z + s1.z) + (s2.z + s3.z);
  o.w = (s0.w + s1.w) + (s2.w + s3.w);
  *(float4*)(ctx + i) = o;
}

extern "C" void kernel_launch(void* const* d_in, const int* in_sizes, int n_in,
                              void* d_out, int out_size, void* d_ws, size_t ws_size,
                              hipStream_t stream) {
  const float* dec = (const float*)d_in[0];
  const float* enc = (const float*)d_in[1];
  const float* W1  = (const float*)d_in[2];
  const float* b1  = (const float*)d_in[3];
  const float* W2  = (const float*)d_in[4];
  const float* b2  = (const float*)d_in[5];
  const float* v   = (const float*)d_in[6];
  // d_in[7] = v_b: skipped — softmax is invariant to a uniform score shift.

  float* ctx  = (float*)d_out;                        // [4,128,512]
  float* attn = (float*)d_out + (size_t)NB * TD * DD; // [4,128,1024]

  float* ws    = (float*)d_ws;
  float* wencT = ws;                                  // [4][128][1024] 2 MB
  float* wdec  = wencT + (size_t)NB * UN * SE;        // [512][128] 256 KB
  // scratch area shared in time: first proj partials (9 MB), later ctx partials (4 MB)
  float* scratch = wdec + (size_t)NB * TD * UN;
  float* projpart = scratch;                          // [4][4608][128]
  float* ctxpart  = scratch;                          // [4][512][512]

  hipLaunchKernelGGL(k_proj_part, dim3(288, KSPLIT), dim3(256), 0, stream,
                     enc, dec, W1, W2, projpart);
  hipLaunchKernelGGL(k_redT, dim3(288), dim3(256), 0, stream,
                     projpart, b1, b2, wencT, wdec);
  hipLaunchKernelGGL(k_score, dim3(256), dim3(512), 0, stream,
                     wdec, v, wencT, attn);
  hipLaunchKernelGGL(k_ctx_part, dim3(256), dim3(256), 0, stream, attn, enc, ctxpart);
  hipLaunchKernelGGL(k_red, dim3(256), dim3(256), 0, stream, ctxpart, ctx);
}

// Round 9
// 71.032 us; speedup vs baseline: 1.7297x; 1.1193x over previous
//
#include <hip/hip_runtime.h>
#include <math.h>

#define NB 4      // batch
#define TD 128    // T_DEC
#define SE 1024   // S_ENC
#define DD 512    // D
#define UN 128    // UNITS
#define NROWS 4608          // 4096 enc + 512 dec
#define KSPLIT 4
#define SSPLIT 8            // ctx s-chunks

// tanh(x) = 1 - 2/(exp(2x)+1). exp via __expf (v_exp); rcp via v_rcp.
// Stable at +-inf; rel err ~1e-5 << 3e-3 tolerance.

// ---------------------------------------------------------------------------
// K1a: projection partials. grid (288, 4): blockIdx.x = row-block (16 rows),
// blockIdx.y = ks (K slice of 128). blk 0..255 -> enc rows, 256..287 -> dec.
// Stage 16 rows x 128 k (8 KB) in LDS; thread = (u2, 4 rows). Per k-quad:
// 4 coalesced float2 W loads + 32 FMA in 8 chains. 1152 WGs = 18 waves/CU.
__global__ __launch_bounds__(256, 4) void k_proj_part(const float* __restrict__ enc,
                                                      const float* __restrict__ dec,
                                                      const float* __restrict__ W1,
                                                      const float* __restrict__ W2,
                                                      float* __restrict__ part) {
  __shared__ __align__(16) float At[16 * 128];   // 8 KB

  const int tx = threadIdx.x;
  const int rb = blockIdx.x;            // 0..287
  const int ks = blockIdx.y;            // 0..3
  const bool is_enc = rb < 256;
  const int row_base = rb * 16;         // global row numbering 0..4607
  const float* __restrict__ src = is_enc
      ? (enc + (size_t)row_base * DD)
      : (dec + (size_t)(row_base - NB * SE) * DD);
  const float* __restrict__ W = is_enc ? W1 : W2;
  const int kb = ks * 128;

  // stage: 16 rows x 128 k = 512 float4, 2 per thread, 128B coalesced runs
#pragma unroll
  for (int i = 0; i < 2; ++i) {
    const int idx = i * 256 + tx;       // 0..511
    const int row = idx >> 5;           // 32 float4 per row
    const int c4 = (idx & 31) * 4;
    *(float4*)&At[row * 128 + c4] = *(const float4*)(src + (size_t)row * DD + kb + c4);
  }
  __syncthreads();

  const int u2 = (tx & 63) * 2;
  const int r0 = (tx >> 6) * 4;         // wave-uniform row group
  const float* __restrict__ Wp = W + (size_t)kb * UN + u2;

  float acc[4][2] = {};
#pragma unroll 2
  for (int k = 0; k < 128; k += 4) {
    float4 a[4];
#pragma unroll
    for (int r = 0; r < 4; ++r)
      a[r] = *(const float4*)&At[(r0 + r) * 128 + k];   // wave-uniform broadcast
#pragma unroll
    for (int j = 0; j < 4; ++j) {
      const float2 w = *(const float2*)(Wp + (size_t)(k + j) * UN);
#pragma unroll
      for (int r = 0; r < 4; ++r) {
        const float arj = ((const float*)&a[r])[j];
        acc[r][0] = fmaf(arj, w.x, acc[r][0]);
        acc[r][1] = fmaf(arj, w.y, acc[r][1]);
      }
    }
  }

  float* pb = part + ((size_t)ks * NROWS + row_base + r0) * UN + u2;
#pragma unroll
  for (int r = 0; r < 4; ++r)
    *(float2*)(pb + (size_t)r * UN) = make_float2(acc[r][0], acc[r][1]);
}

// ---------------------------------------------------------------------------
// K1b: reduce 4 K-partials + bias; enc rows -> wencT (transposed via LDS),
// dec rows -> wdec. grid 288 x 256 thr; thread sums 8 u of one row.
__global__ __launch_bounds__(256, 4) void k_redT(const float* __restrict__ part,
                                                 const float* __restrict__ b1,
                                                 const float* __restrict__ b2,
                                                 float* __restrict__ wencT,
                                                 float* __restrict__ wdec) {
  __shared__ __align__(16) float Tt[16][132];
  const int tx = threadIdx.x;
  const int rb = blockIdx.x;
  const int row_base = rb * 16;
  const bool is_enc = rb < 256;
  const int r = tx >> 4;                // 0..15
  const int u0 = (tx & 15) * 8;         // 8 u per thread
  const size_t N = (size_t)NROWS * UN;

  const float* p = part + (size_t)(row_base + r) * UN + u0;
  float4 sa = *(const float4*)(p);
  float4 sb = *(const float4*)(p + 4);
#pragma unroll
  for (int s = 1; s < KSPLIT; ++s) {
    const float4 qa = *(const float4*)(p + (size_t)s * N);
    const float4 qb = *(const float4*)(p + (size_t)s * N + 4);
    sa.x += qa.x; sa.y += qa.y; sa.z += qa.z; sa.w += qa.w;
    sb.x += qb.x; sb.y += qb.y; sb.z += qb.z; sb.w += qb.w;
  }
  const float* bias = is_enc ? b1 : b2;
  const float4 ba = *(const float4*)(bias + u0);
  const float4 bb = *(const float4*)(bias + u0 + 4);
  sa.x += ba.x; sa.y += ba.y; sa.z += ba.z; sa.w += ba.w;
  sb.x += bb.x; sb.y += bb.y; sb.z += bb.z; sb.w += bb.w;

  if (is_enc) {
    *(float4*)&Tt[r][u0] = sa;
    *(float4*)&Tt[r][u0 + 4] = sb;
    __syncthreads();
    const int b = row_base >> 10;
    const int s0 = row_base & 1023;
    const int u = tx >> 1;
    const int sh = tx & 1;
    float o[8];
#pragma unroll
    for (int j = 0; j < 8; ++j) o[j] = Tt[sh * 8 + j][u];
    float* dst = wencT + (size_t)(b * UN + u) * SE + s0 + sh * 8;
    *(float4*)dst = make_float4(o[0], o[1], o[2], o[3]);
    *(float4*)(dst + 4) = make_float4(o[4], o[5], o[6], o[7]);
  } else {
    float* dst = wdec + (size_t)(row_base - NB * SE + r) * UN + u0;
    *(float4*)dst = sa;
    *(float4*)(dst + 4) = sb;
  }
}

// ---------------------------------------------------------------------------
// K2: scores + softmax. One WG (1024 thr, 16 waves) per (b, t-pair): grid 256
// -> 4 waves/SIMD. Thread: 2 t x 4 s x 32 u (u-quarter by tx>>8).
// wencT[b][u][s] stream fully coalesced; 8 tanh per float4 load.
// v_b skipped (softmax shift-invariant).
__global__ __launch_bounds__(1024, 1) void k_score(const float* __restrict__ wdec,
                                                   const float* __restrict__ v,
                                                   const float* __restrict__ wencT,
                                                   float* __restrict__ attn) {
  __shared__ __align__(16) float wd2[2][UN];        // 2*wdec row
  __shared__ __align__(16) float vsh[UN];
  __shared__ __align__(16) float parts[4][2][SE];   // [uq][tt][s]  32 KB
  __shared__ float redM[2][4], redS[2][4];

  const int wg = blockIdx.x;          // 0..255
  const int b = wg >> 6;
  const int t0 = (wg & 63) * 2;
  const int bt0 = b * TD + t0;
  const int tx = threadIdx.x;         // 0..1023

  if (tx < 2 * UN) {
    const int tt = tx >> 7, u = tx & 127;
    wd2[tt][u] = 2.0f * wdec[(size_t)(bt0 + tt) * UN + u];
    if (tx < UN) vsh[tx] = v[tx];
  }
  __syncthreads();

  const int sq = tx & 255;            // s-quad 0..255
  const int uq = tx >> 8;             // u quarter 0..3
  const float* wp = wencT + (size_t)(b * UN + uq * 32) * SE + sq * 4;

  float a0[4] = {}, a1[4] = {};
#pragma unroll 4
  for (int ui = 0; ui < 32; ++ui) {
    const int u = uq * 32 + ui;
    const float4 w = *(const float4*)(wp + (size_t)ui * SE);
    const float vv = vsh[u];
    const float d0 = wd2[0][u];
    const float d1 = wd2[1][u];
#pragma unroll
    for (int j = 0; j < 4; ++j) {
      const float wj = ((const float*)&w)[j];
      float e0 = __expf(fmaf(wj, 2.0f, d0));
      float t0v = fmaf(-2.0f, __builtin_amdgcn_rcpf(e0 + 1.0f), 1.0f);
      a0[j] = fmaf(vv, t0v, a0[j]);
      float e1 = __expf(fmaf(wj, 2.0f, d1));
      float t1v = fmaf(-2.0f, __builtin_amdgcn_rcpf(e1 + 1.0f), 1.0f);
      a1[j] = fmaf(vv, t1v, a1[j]);
    }
  }
  *(float4*)&parts[uq][0][sq * 4] = make_float4(a0[0], a0[1], a0[2], a0[3]);
  *(float4*)&parts[uq][1][sq * 4] = make_float4(a1[0], a1[1], a1[2], a1[3]);
  __syncthreads();

  // threads 0..511: tt = tx>>8, q = tx&255 -> 4 s-values each
  float sc[4], pv[4];
  const int tt = tx >> 8;             // valid for tx<512
  const int q = tx & 255;
  if (tx < 512) {
    const float4 g0 = *(const float4*)&parts[0][tt][q * 4];
    const float4 g1 = *(const float4*)&parts[1][tt][q * 4];
    const float4 g2 = *(const float4*)&parts[2][tt][q * 4];
    const float4 g3 = *(const float4*)&parts[3][tt][q * 4];
    sc[0] = (g0.x + g1.x) + (g2.x + g3.x);
    sc[1] = (g0.y + g1.y) + (g2.y + g3.y);
    sc[2] = (g0.z + g1.z) + (g2.z + g3.z);
    sc[3] = (g0.w + g1.w) + (g2.w + g3.w);
    float m = fmaxf(fmaxf(sc[0], sc[1]), fmaxf(sc[2], sc[3]));
#pragma unroll
    for (int off = 32; off; off >>= 1) m = fmaxf(m, __shfl_xor(m, off));
    if ((tx & 63) == 0) redM[tt][(tx >> 6) & 3] = m;
  }
  __syncthreads();
  if (tx < 512) {
    const float m = fmaxf(fmaxf(redM[tt][0], redM[tt][1]),
                          fmaxf(redM[tt][2], redM[tt][3]));
    float s = 0.f;
#pragma unroll
    for (int j = 0; j < 4; ++j) { pv[j] = __expf(sc[j] - m); s += pv[j]; }
#pragma unroll
    for (int off = 32; off; off >>= 1) s += __shfl_xor(s, off);
    if ((tx & 63) == 0) redS[tt][(tx >> 6) & 3] = s;
  }
  __syncthreads();
  if (tx < 512) {
    const float s = (redS[tt][0] + redS[tt][1]) + (redS[tt][2] + redS[tt][3]);
    const float rinv = 1.0f / s;
    float* arow = attn + (size_t)(bt0 + tt) * SE + q * 4;
    *(float4*)arow = make_float4(pv[0] * rinv, pv[1] * rinv, pv[2] * rinv, pv[3] * rinv);
  }
}

// ---------------------------------------------------------------------------
// K3: partial context over s-chunks of 128. grid = sc(8) x tg(16) x b(4) = 512.
// WG: 8 t-rows x all 512 d; thread = 8t x 2d (16 fma per enc float2 load).
// attn tile (8x128 = 4 KB) staged in LDS, read as all-lane broadcasts.
__global__ __launch_bounds__(256, 2) void k_ctx_part(const float* __restrict__ attn,
                                                     const float* __restrict__ enc,
                                                     float* __restrict__ part) {
  __shared__ __align__(16) float at[8][128];
  const int wg = blockIdx.x;
  const int sch = wg & 7;
  const int tg = (wg >> 3) & 15;
  const int b = wg >> 7;
  const int tx = threadIdx.x;
  const int sbeg = sch * 128;
  {
    const int i = tx >> 5, c = (tx & 31) * 4;   // 8 rows x 32 float4
    *(float4*)&at[i][c] =
        *(const float4*)(attn + (size_t)(b * TD + tg * 8 + i) * SE + sbeg + c);
  }
  __syncthreads();
  const int d0 = tx * 2;
  const float* ep = enc + ((size_t)b * SE + sbeg) * DD + d0;
  float2 acc[8] = {};
  for (int s = 0; s < 128; s += 4) {
    float4 av[8];
#pragma unroll
    for (int i = 0; i < 8; ++i) av[i] = *(const float4*)&at[i][s];
#pragma unroll
    for (int j = 0; j < 4; ++j) {
      const float2 ev = *(const float2*)(ep + (size_t)(s + j) * DD);
#pragma unroll
      for (int i = 0; i < 8; ++i) {
        const float aij = ((const float*)&av[i])[j];
        acc[i].x = fmaf(aij, ev.x, acc[i].x);
        acc[i].y = fmaf(aij, ev.y, acc[i].y);
      }
    }
  }
  float* pb = part + ((size_t)sch * (NB * TD) + b * TD + tg * 8) * DD + d0;
#pragma unroll
  for (int i = 0; i < 8; ++i)
    *(float2*)(pb + (size_t)i * DD) = acc[i];
}

// ---------------------------------------------------------------------------
// K4: ctx = sum of 8 partials. grid 256 x 256 thr, float4/thread.
__global__ __launch_bounds__(256, 2) void k_red(const float* __restrict__ part,
                                                float* __restrict__ ctx) {
  const size_t N = (size_t)NB * TD * DD;
  const size_t i = ((size_t)blockIdx.x * 256 + threadIdx.x) * 4;
  float4 o = *(const float4*)(part + i);
#pragma unroll
  for (int s = 1; s < SSPLIT; ++s) {
    const float4 q = *(const float4*)(part + (size_t)s * N + i);
    o.x += q.x; o.y += q.y; o.z += q.z; o.w += q.w;
  }
  *(float4*)(ctx + i) = o;
}

extern "C" void kernel_launch(void* const* d_in, const int* in_sizes, int n_in,
                              void* d_out, int out_size, void* d_ws, size_t ws_size,
                              hipStream_t stream) {
  const float* dec = (const float*)d_in[0];
  const float* enc = (const float*)d_in[1];
  const float* W1  = (const float*)d_in[2];
  const float* b1  = (const float*)d_in[3];
  const float* W2  = (const float*)d_in[4];
  const float* b2  = (const float*)d_in[5];
  const float* v   = (const float*)d_in[6];
  // d_in[7] = v_b: skipped — softmax is invariant to a uniform score shift.

  float* ctx  = (float*)d_out;                        // [4,128,512]
  float* attn = (float*)d_out + (size_t)NB * TD * DD; // [4,128,1024]

  float* ws    = (float*)d_ws;
  float* wencT = ws;                                  // [4][128][1024] 2 MB
  float* wdec  = wencT + (size_t)NB * UN * SE;        // [512][128] 256 KB
  // scratch shared in time: proj partials (9 MB) then ctx partials (8 MB)
  float* scratch = wdec + (size_t)NB * TD * UN;
  float* projpart = scratch;                          // [4][4608][128]
  float* ctxpart  = scratch;                          // [8][512][512]

  hipLaunchKernelGGL(k_proj_part, dim3(288, KSPLIT), dim3(256), 0, stream,
                     enc, dec, W1, W2, projpart);
  hipLaunchKernelGGL(k_redT, dim3(288), dim3(256), 0, stream,
                     projpart, b1, b2, wencT, wdec);
  hipLaunchKernelGGL(k_score, dim3(256), dim3(1024), 0, stream,
                     wdec, v, wencT, attn);
  hipLaunchKernelGGL(k_ctx_part, dim3(512), dim3(256), 0, stream, attn, enc, ctxpart);
  hipLaunchKernelGGL(k_red, dim3(256), dim3(256), 0, stream, ctxpart, ctx);
}

// Round 10
// 65.130 us; speedup vs baseline: 1.8864x; 1.0906x over previous
//
#include <hip/hip_runtime.h>
#include <math.h>

#define NB 4      // batch
#define TD 128    // T_DEC
#define SE 1024   // S_ENC
#define DD 512    // D
#define UN 128    // UNITS
#define NROWS 4608          // 4096 enc + 512 dec
#define KSPLIT 4
#define SSPLIT 8            // ctx s-chunks

// tanh(x) = 1 - 2/(exp(2x)+1). exp via __expf (v_exp); rcp via v_rcp.
// Stable at +-inf; rel err ~1e-5 << 3e-3 tolerance.

// ---------------------------------------------------------------------------
// K1a: projection partials. grid (144, 4): blockIdx.x = row-block (32 rows),
// blockIdx.y = ks (K slice of 128). blk 0..127 -> enc rows, 128..143 -> dec.
// Stage 32 rows x 128 k (16 KB) in LDS; thread = (u2, 8 rows): 16 FMA per
// coalesced float2 W load, 8 indep chains. W traffic = 4608/8 waves x 64 KB
// = 147 MB L2 (half of round-9).
__global__ __launch_bounds__(256, 4) void k_proj_part(const float* __restrict__ enc,
                                                      const float* __restrict__ dec,
                                                      const float* __restrict__ W1,
                                                      const float* __restrict__ W2,
                                                      float* __restrict__ part) {
  __shared__ __align__(16) float At[32 * 128];   // 16 KB

  const int tx = threadIdx.x;
  const int rb = blockIdx.x;            // 0..143
  const int ks = blockIdx.y;            // 0..3
  const bool is_enc = rb < 128;
  const int row_base = rb * 32;         // global row numbering 0..4607
  const float* __restrict__ src = is_enc
      ? (enc + (size_t)row_base * DD)
      : (dec + (size_t)(row_base - NB * SE) * DD);
  const float* __restrict__ W = is_enc ? W1 : W2;
  const int kb = ks * 128;

  // stage: 32 rows x 128 k = 1024 float4, 4 per thread, 128B coalesced runs
#pragma unroll
  for (int i = 0; i < 4; ++i) {
    const int idx = i * 256 + tx;       // 0..1023
    const int row = idx >> 5;           // 32 float4 per row
    const int c4 = (idx & 31) * 4;
    *(float4*)&At[row * 128 + c4] = *(const float4*)(src + (size_t)row * DD + kb + c4);
  }
  __syncthreads();

  const int u2 = (tx & 63) * 2;
  const int r0 = (tx >> 6) * 8;         // wave-uniform row group (8 rows)
  const float* __restrict__ Wp = W + (size_t)kb * UN + u2;

  float acc[8][2] = {};
  for (int k = 0; k < 128; k += 4) {
    float4 a[8];
#pragma unroll
    for (int r = 0; r < 8; ++r)
      a[r] = *(const float4*)&At[(r0 + r) * 128 + k];   // wave-uniform broadcast
#pragma unroll
    for (int j = 0; j < 4; ++j) {
      const float2 w = *(const float2*)(Wp + (size_t)(k + j) * UN);
#pragma unroll
      for (int r = 0; r < 8; ++r) {
        const float arj = ((const float*)&a[r])[j];
        acc[r][0] = fmaf(arj, w.x, acc[r][0]);
        acc[r][1] = fmaf(arj, w.y, acc[r][1]);
      }
    }
  }

  float* pb = part + ((size_t)ks * NROWS + row_base + r0) * UN + u2;
#pragma unroll
  for (int r = 0; r < 8; ++r)
    *(float2*)(pb + (size_t)r * UN) = make_float2(acc[r][0], acc[r][1]);
}

// ---------------------------------------------------------------------------
// K1b: reduce 4 K-partials + bias; enc rows -> wencT (transposed via LDS),
// dec rows -> wdec. grid 288 x 256 thr; thread sums 8 u of one row.
__global__ __launch_bounds__(256, 4) void k_redT(const float* __restrict__ part,
                                                 const float* __restrict__ b1,
                                                 const float* __restrict__ b2,
                                                 float* __restrict__ wencT,
                                                 float* __restrict__ wdec) {
  __shared__ __align__(16) float Tt[16][132];
  const int tx = threadIdx.x;
  const int rb = blockIdx.x;
  const int row_base = rb * 16;
  const bool is_enc = rb < 256;
  const int r = tx >> 4;                // 0..15
  const int u0 = (tx & 15) * 8;         // 8 u per thread
  const size_t N = (size_t)NROWS * UN;

  const float* p = part + (size_t)(row_base + r) * UN + u0;
  float4 sa = *(const float4*)(p);
  float4 sb = *(const float4*)(p + 4);
#pragma unroll
  for (int s = 1; s < KSPLIT; ++s) {
    const float4 qa = *(const float4*)(p + (size_t)s * N);
    const float4 qb = *(const float4*)(p + (size_t)s * N + 4);
    sa.x += qa.x; sa.y += qa.y; sa.z += qa.z; sa.w += qa.w;
    sb.x += qb.x; sb.y += qb.y; sb.z += qb.z; sb.w += qb.w;
  }
  const float* bias = is_enc ? b1 : b2;
  const float4 ba = *(const float4*)(bias + u0);
  const float4 bb = *(const float4*)(bias + u0 + 4);
  sa.x += ba.x; sa.y += ba.y; sa.z += ba.z; sa.w += ba.w;
  sb.x += bb.x; sb.y += bb.y; sb.z += bb.z; sb.w += bb.w;

  if (is_enc) {
    *(float4*)&Tt[r][u0] = sa;
    *(float4*)&Tt[r][u0 + 4] = sb;
    __syncthreads();
    const int b = row_base >> 10;
    const int s0 = row_base & 1023;
    const int u = tx >> 1;
    const int sh = tx & 1;
    float o[8];
#pragma unroll
    for (int j = 0; j < 8; ++j) o[j] = Tt[sh * 8 + j][u];
    float* dst = wencT + (size_t)(b * UN + u) * SE + s0 + sh * 8;
    *(float4*)dst = make_float4(o[0], o[1], o[2], o[3]);
    *(float4*)(dst + 4) = make_float4(o[4], o[5], o[6], o[7]);
  } else {
    float* dst = wdec + (size_t)(row_base - NB * SE + r) * UN + u0;
    *(float4*)dst = sa;
    *(float4*)(dst + 4) = sb;
  }
}

// ---------------------------------------------------------------------------
// K2: scores + softmax. One WG (1024 thr, 16 waves) per (b, t-pair): grid 256
// -> 4 waves/SIMD. Thread: 2 t x 4 s x 32 u (u-quarter by tx>>8).
// wencT[b][u][s] stream fully coalesced; 8 tanh per float4 load.
// v_b skipped (softmax shift-invariant).
__global__ __launch_bounds__(1024, 1) void k_score(const float* __restrict__ wdec,
                                                   const float* __restrict__ v,
                                                   const float* __restrict__ wencT,
                                                   float* __restrict__ attn) {
  __shared__ __align__(16) float wd2[2][UN];        // 2*wdec row
  __shared__ __align__(16) float vsh[UN];
  __shared__ __align__(16) float parts[4][2][SE];   // [uq][tt][s]  32 KB
  __shared__ float redM[2][4], redS[2][4];

  const int wg = blockIdx.x;          // 0..255
  const int b = wg >> 6;
  const int t0 = (wg & 63) * 2;
  const int bt0 = b * TD + t0;
  const int tx = threadIdx.x;         // 0..1023

  if (tx < 2 * UN) {
    const int tt = tx >> 7, u = tx & 127;
    wd2[tt][u] = 2.0f * wdec[(size_t)(bt0 + tt) * UN + u];
    if (tx < UN) vsh[tx] = v[tx];
  }
  __syncthreads();

  const int sq = tx & 255;            // s-quad 0..255
  const int uq = tx >> 8;             // u quarter 0..3
  const float* wp = wencT + (size_t)(b * UN + uq * 32) * SE + sq * 4;

  float a0[4] = {}, a1[4] = {};
#pragma unroll 4
  for (int ui = 0; ui < 32; ++ui) {
    const int u = uq * 32 + ui;
    const float4 w = *(const float4*)(wp + (size_t)ui * SE);
    const float vv = vsh[u];
    const float d0 = wd2[0][u];
    const float d1 = wd2[1][u];
#pragma unroll
    for (int j = 0; j < 4; ++j) {
      const float wj = ((const float*)&w)[j];
      float e0 = __expf(fmaf(wj, 2.0f, d0));
      float t0v = fmaf(-2.0f, __builtin_amdgcn_rcpf(e0 + 1.0f), 1.0f);
      a0[j] = fmaf(vv, t0v, a0[j]);
      float e1 = __expf(fmaf(wj, 2.0f, d1));
      float t1v = fmaf(-2.0f, __builtin_amdgcn_rcpf(e1 + 1.0f), 1.0f);
      a1[j] = fmaf(vv, t1v, a1[j]);
    }
  }
  *(float4*)&parts[uq][0][sq * 4] = make_float4(a0[0], a0[1], a0[2], a0[3]);
  *(float4*)&parts[uq][1][sq * 4] = make_float4(a1[0], a1[1], a1[2], a1[3]);
  __syncthreads();

  // threads 0..511: tt = tx>>8, q = tx&255 -> 4 s-values each
  float sc[4], pv[4];
  const int tt = tx >> 8;             // valid for tx<512
  const int q = tx & 255;
  if (tx < 512) {
    const float4 g0 = *(const float4*)&parts[0][tt][q * 4];
    const float4 g1 = *(const float4*)&parts[1][tt][q * 4];
    const float4 g2 = *(const float4*)&parts[2][tt][q * 4];
    const float4 g3 = *(const float4*)&parts[3][tt][q * 4];
    sc[0] = (g0.x + g1.x) + (g2.x + g3.x);
    sc[1] = (g0.y + g1.y) + (g2.y + g3.y);
    sc[2] = (g0.z + g1.z) + (g2.z + g3.z);
    sc[3] = (g0.w + g1.w) + (g2.w + g3.w);
    float m = fmaxf(fmaxf(sc[0], sc[1]), fmaxf(sc[2], sc[3]));
#pragma unroll
    for (int off = 32; off; off >>= 1) m = fmaxf(m, __shfl_xor(m, off));
    if ((tx & 63) == 0) redM[tt][(tx >> 6) & 3] = m;
  }
  __syncthreads();
  if (tx < 512) {
    const float m = fmaxf(fmaxf(redM[tt][0], redM[tt][1]),
                          fmaxf(redM[tt][2], redM[tt][3]));
    float s = 0.f;
#pragma unroll
    for (int j = 0; j < 4; ++j) { pv[j] = __expf(sc[j] - m); s += pv[j]; }
#pragma unroll
    for (int off = 32; off; off >>= 1) s += __shfl_xor(s, off);
    if ((tx & 63) == 0) redS[tt][(tx >> 6) & 3] = s;
  }
  __syncthreads();
  if (tx < 512) {
    const float s = (redS[tt][0] + redS[tt][1]) + (redS[tt][2] + redS[tt][3]);
    const float rinv = 1.0f / s;
    float* arow = attn + (size_t)(bt0 + tt) * SE + q * 4;
    *(float4*)arow = make_float4(pv[0] * rinv, pv[1] * rinv, pv[2] * rinv, pv[3] * rinv);
  }
}

// ---------------------------------------------------------------------------
// K3: partial context over s-chunks of 128. grid = sc(8) x tg(16) x b(4) = 512.
// WG: 8 t-rows x all 512 d; thread = 8t x 2d (16 fma per enc float2 load).
// attn tile (8x128 = 4 KB) staged in LDS, read as all-lane broadcasts.
__global__ __launch_bounds__(256, 2) void k_ctx_part(const float* __restrict__ attn,
                                                     const float* __restrict__ enc,
                                                     float* __restrict__ part) {
  __shared__ __align__(16) float at[8][128];
  const int wg = blockIdx.x;
  const int sch = wg & 7;
  const int tg = (wg >> 3) & 15;
  const int b = wg >> 7;
  const int tx = threadIdx.x;
  const int sbeg = sch * 128;
  {
    const int i = tx >> 5, c = (tx & 31) * 4;   // 8 rows x 32 float4
    *(float4*)&at[i][c] =
        *(const float4*)(attn + (size_t)(b * TD + tg * 8 + i) * SE + sbeg + c);
  }
  __syncthreads();
  const int d0 = tx * 2;
  const float* ep = enc + ((size_t)b * SE + sbeg) * DD + d0;
  float2 acc[8] = {};
  for (int s = 0; s < 128; s += 4) {
    float4 av[8];
#pragma unroll
    for (int i = 0; i < 8; ++i) av[i] = *(const float4*)&at[i][s];
#pragma unroll
    for (int j = 0; j < 4; ++j) {
      const float2 ev = *(const float2*)(ep + (size_t)(s + j) * DD);
#pragma unroll
      for (int i = 0; i < 8; ++i) {
        const float aij = ((const float*)&av[i])[j];
        acc[i].x = fmaf(aij, ev.x, acc[i].x);
        acc[i].y = fmaf(aij, ev.y, acc[i].y);
      }
    }
  }
  float* pb = part + ((size_t)sch * (NB * TD) + b * TD + tg * 8) * DD + d0;
#pragma unroll
  for (int i = 0; i < 8; ++i)
    *(float2*)(pb + (size_t)i * DD) = acc[i];
}

// ---------------------------------------------------------------------------
// K4: ctx = sum of 8 partials. grid 256 x 256 thr, float4/thread.
__global__ __launch_bounds__(256, 2) void k_red(const float* __restrict__ part,
                                                float* __restrict__ ctx) {
  const size_t N = (size_t)NB * TD * DD;
  const size_t i = ((size_t)blockIdx.x * 256 + threadIdx.x) * 4;
  float4 o = *(const float4*)(part + i);
#pragma unroll
  for (int s = 1; s < SSPLIT; ++s) {
    const float4 q = *(const float4*)(part + (size_t)s * N + i);
    o.x += q.x; o.y += q.y; o.z += q.z; o.w += q.w;
  }
  *(float4*)(ctx + i) = o;
}

extern "C" void kernel_launch(void* const* d_in, const int* in_sizes, int n_in,
                              void* d_out, int out_size, void* d_ws, size_t ws_size,
                              hipStream_t stream) {
  const float* dec = (const float*)d_in[0];
  const float* enc = (const float*)d_in[1];
  const float* W1  = (const float*)d_in[2];
  const float* b1  = (const float*)d_in[3];
  const float* W2  = (const float*)d_in[4];
  const float* b2  = (const float*)d_in[5];
  const float* v   = (const float*)d_in[6];
  // d_in[7] = v_b: skipped — softmax is invariant to a uniform score shift.

  float* ctx  = (float*)d_out;                        // [4,128,512]
  float* attn = (float*)d_out + (size_t)NB * TD * DD; // [4,128,1024]

  float* ws    = (float*)d_ws;
  float* wencT = ws;                                  // [4][128][1024] 2 MB
  float* wdec  = wencT + (size_t)NB * UN * SE;        // [512][128] 256 KB
  // scratch shared in time: proj partials (9 MB) then ctx partials (8 MB)
  float* scratch = wdec + (size_t)NB * TD * UN;
  float* projpart = scratch;                          // [4][4608][128]
  float* ctxpart  = scratch;                          // [8][512][512]

  hipLaunchKernelGGL(k_proj_part, dim3(144, KSPLIT), dim3(256), 0, stream,
                     enc, dec, W1, W2, projpart);
  hipLaunchKernelGGL(k_redT, dim3(288), dim3(256), 0, stream,
                     projpart, b1, b2, wencT, wdec);
  hipLaunchKernelGGL(k_score, dim3(256), dim3(1024), 0, stream,
                     wdec, v, wencT, attn);
  hipLaunchKernelGGL(k_ctx_part, dim3(512), dim3(256), 0, stream, attn, enc, ctxpart);
  hipLaunchKernelGGL(k_red, dim3(256), dim3(256), 0, stream, ctxpart, ctx);
}

// Round 11
// 61.306 us; speedup vs baseline: 2.0041x; 1.0624x over previous
//
#include <hip/hip_runtime.h>
#include <math.h>

#define NB 4      // batch
#define TD 128    // T_DEC
#define SE 1024   // S_ENC
#define DD 512    // D
#define UN 128    // UNITS
#define NROWS 4608          // 4096 enc + 512 dec
#define KSPLIT 4
#define SSPLIT 8            // ctx s-chunks

// raw v_exp_f32: D = 2^S0 (we pre-scale by 2*log2e in the operands)
__device__ __forceinline__ float exp2_raw(float x) {
  float r;
  asm("v_exp_f32 %0, %1" : "=v"(r) : "v"(x));
  return r;
}

// ---------------------------------------------------------------------------
// K1a: projection partials. grid (144, 4): blockIdx.x = row-block (32 rows),
// blockIdx.y = ks (K slice of 128). blk 0..127 -> enc rows, 128..143 -> dec.
// Stage 32 rows x 128 k (16 KB) in LDS; thread = (u2, 8 rows): 16 FMA per
// coalesced float2 W load, 8 indep chains.
__global__ __launch_bounds__(256, 4) void k_proj_part(const float* __restrict__ enc,
                                                      const float* __restrict__ dec,
                                                      const float* __restrict__ W1,
                                                      const float* __restrict__ W2,
                                                      float* __restrict__ part) {
  __shared__ __align__(16) float At[32 * 128];   // 16 KB

  const int tx = threadIdx.x;
  const int rb = blockIdx.x;            // 0..143
  const int ks = blockIdx.y;            // 0..3
  const bool is_enc = rb < 128;
  const int row_base = rb * 32;         // global row numbering 0..4607
  const float* __restrict__ src = is_enc
      ? (enc + (size_t)row_base * DD)
      : (dec + (size_t)(row_base - NB * SE) * DD);
  const float* __restrict__ W = is_enc ? W1 : W2;
  const int kb = ks * 128;

#pragma unroll
  for (int i = 0; i < 4; ++i) {
    const int idx = i * 256 + tx;       // 0..1023
    const int row = idx >> 5;           // 32 float4 per row
    const int c4 = (idx & 31) * 4;
    *(float4*)&At[row * 128 + c4] = *(const float4*)(src + (size_t)row * DD + kb + c4);
  }
  __syncthreads();

  const int u2 = (tx & 63) * 2;
  const int r0 = (tx >> 6) * 8;         // wave-uniform row group (8 rows)
  const float* __restrict__ Wp = W + (size_t)kb * UN + u2;

  float acc[8][2] = {};
  for (int k = 0; k < 128; k += 4) {
    float4 a[8];
#pragma unroll
    for (int r = 0; r < 8; ++r)
      a[r] = *(const float4*)&At[(r0 + r) * 128 + k];   // wave-uniform broadcast
#pragma unroll
    for (int j = 0; j < 4; ++j) {
      const float2 w = *(const float2*)(Wp + (size_t)(k + j) * UN);
#pragma unroll
      for (int r = 0; r < 8; ++r) {
        const float arj = ((const float*)&a[r])[j];
        acc[r][0] = fmaf(arj, w.x, acc[r][0]);
        acc[r][1] = fmaf(arj, w.y, acc[r][1]);
      }
    }
  }

  float* pb = part + ((size_t)ks * NROWS + row_base + r0) * UN + u2;
#pragma unroll
  for (int r = 0; r < 8; ++r)
    *(float2*)(pb + (size_t)r * UN) = make_float2(acc[r][0], acc[r][1]);
}

// ---------------------------------------------------------------------------
// K1b: reduce 4 K-partials + bias; enc rows -> wencT (transposed via LDS),
// dec rows -> wdec. grid 288 x 256 thr; thread sums 8 u of one row.
__global__ __launch_bounds__(256, 4) void k_redT(const float* __restrict__ part,
                                                 const float* __restrict__ b1,
                                                 const float* __restrict__ b2,
                                                 float* __restrict__ wencT,
                                                 float* __restrict__ wdec) {
  __shared__ __align__(16) float Tt[16][132];
  const int tx = threadIdx.x;
  const int rb = blockIdx.x;
  const int row_base = rb * 16;
  const bool is_enc = rb < 256;
  const int r = tx >> 4;                // 0..15
  const int u0 = (tx & 15) * 8;         // 8 u per thread
  const size_t N = (size_t)NROWS * UN;

  const float* p = part + (size_t)(row_base + r) * UN + u0;
  float4 sa = *(const float4*)(p);
  float4 sb = *(const float4*)(p + 4);
#pragma unroll
  for (int s = 1; s < KSPLIT; ++s) {
    const float4 qa = *(const float4*)(p + (size_t)s * N);
    const float4 qb = *(const float4*)(p + (size_t)s * N + 4);
    sa.x += qa.x; sa.y += qa.y; sa.z += qa.z; sa.w += qa.w;
    sb.x += qb.x; sb.y += qb.y; sb.z += qb.z; sb.w += qb.w;
  }
  const float* bias = is_enc ? b1 : b2;
  const float4 ba = *(const float4*)(bias + u0);
  const float4 bb = *(const float4*)(bias + u0 + 4);
  sa.x += ba.x; sa.y += ba.y; sa.z += ba.z; sa.w += ba.w;
  sb.x += bb.x; sb.y += bb.y; sb.z += bb.z; sb.w += bb.w;

  if (is_enc) {
    *(float4*)&Tt[r][u0] = sa;
    *(float4*)&Tt[r][u0 + 4] = sb;
    __syncthreads();
    const int b = row_base >> 10;
    const int s0 = row_base & 1023;
    const int u = tx >> 1;
    const int sh = tx & 1;
    float o[8];
#pragma unroll
    for (int j = 0; j < 8; ++j) o[j] = Tt[sh * 8 + j][u];
    float* dst = wencT + (size_t)(b * UN + u) * SE + s0 + sh * 8;
    *(float4*)dst = make_float4(o[0], o[1], o[2], o[3]);
    *(float4*)(dst + 4) = make_float4(o[4], o[5], o[6], o[7]);
  } else {
    float* dst = wdec + (size_t)(row_base - NB * SE + r) * UN + u0;
    *(float4*)dst = sa;
    *(float4*)(dst + 4) = sb;
  }
}

// ---------------------------------------------------------------------------
// K2: scores + softmax. One WG (1024 thr, 16 waves) per (b, t-pair): grid 256.
// Algebra: score' = sum_u (-2 v_u) * rcp(exp2(2log2e*(we+wd)) + 1)
// (the +sum_u v_u constant is dropped -- softmax shift-invariant; v_b too).
// Thread: 2 t x 4 s x 32 u. Per tanh: 3.5 VALU + 2 trans.
__global__ __launch_bounds__(1024, 1) void k_score(const float* __restrict__ wdec,
                                                   const float* __restrict__ v,
                                                   const float* __restrict__ wencT,
                                                   float* __restrict__ attn) {
  __shared__ __align__(16) float wdl[2][UN];        // 2*log2e*wdec rows
  __shared__ __align__(16) float nv2[UN];           // -2*v
  __shared__ __align__(16) float parts[4][2][SE];   // [uq][tt][s]  32 KB
  __shared__ float redM[2][4], redS[2][4];

  const int wg = blockIdx.x;          // 0..255
  const int b = wg >> 6;
  const int t0 = (wg & 63) * 2;
  const int bt0 = b * TD + t0;
  const int tx = threadIdx.x;         // 0..1023
  const float K2 = 2.0f * 1.44269504f;   // 2*log2(e)

  if (tx < 2 * UN) {
    const int tt = tx >> 7, u = tx & 127;
    wdl[tt][u] = K2 * wdec[(size_t)(bt0 + tt) * UN + u];
    if (tx < UN) nv2[tx] = -2.0f * v[tx];
  }
  __syncthreads();

  const int sq = tx & 255;            // s-quad 0..255
  const int uq = tx >> 8;             // u quarter 0..3
  const float* wp = wencT + (size_t)(b * UN + uq * 32) * SE + sq * 4;

  float a0[4] = {}, a1[4] = {};
#pragma unroll 4
  for (int ui = 0; ui < 32; ++ui) {
    const int u = uq * 32 + ui;
    const float4 w = *(const float4*)(wp + (size_t)ui * SE);
    const float nvu = nv2[u];
    const float d0 = wdl[0][u];
    const float d1 = wdl[1][u];
#pragma unroll
    for (int j = 0; j < 4; ++j) {
      const float wjl = ((const float*)&w)[j] * K2;   // shared by both t
      const float r0 = __builtin_amdgcn_rcpf(exp2_raw(wjl + d0) + 1.0f);
      a0[j] = fmaf(nvu, r0, a0[j]);
      const float r1 = __builtin_amdgcn_rcpf(exp2_raw(wjl + d1) + 1.0f);
      a1[j] = fmaf(nvu, r1, a1[j]);
    }
  }
  *(float4*)&parts[uq][0][sq * 4] = make_float4(a0[0], a0[1], a0[2], a0[3]);
  *(float4*)&parts[uq][1][sq * 4] = make_float4(a1[0], a1[1], a1[2], a1[3]);
  __syncthreads();

  // threads 0..511: tt = tx>>8, q = tx&255 -> 4 s-values each
  float sc[4], pv[4];
  const int tt = tx >> 8;             // valid for tx<512
  const int q = tx & 255;
  if (tx < 512) {
    const float4 g0 = *(const float4*)&parts[0][tt][q * 4];
    const float4 g1 = *(const float4*)&parts[1][tt][q * 4];
    const float4 g2 = *(const float4*)&parts[2][tt][q * 4];
    const float4 g3 = *(const float4*)&parts[3][tt][q * 4];
    sc[0] = (g0.x + g1.x) + (g2.x + g3.x);
    sc[1] = (g0.y + g1.y) + (g2.y + g3.y);
    sc[2] = (g0.z + g1.z) + (g2.z + g3.z);
    sc[3] = (g0.w + g1.w) + (g2.w + g3.w);
    float m = fmaxf(fmaxf(sc[0], sc[1]), fmaxf(sc[2], sc[3]));
#pragma unroll
    for (int off = 32; off; off >>= 1) m = fmaxf(m, __shfl_xor(m, off));
    if ((tx & 63) == 0) redM[tt][(tx >> 6) & 3] = m;
  }
  __syncthreads();
  if (tx < 512) {
    const float m = fmaxf(fmaxf(redM[tt][0], redM[tt][1]),
                          fmaxf(redM[tt][2], redM[tt][3]));
    float s = 0.f;
#pragma unroll
    for (int j = 0; j < 4; ++j) { pv[j] = __expf(sc[j] - m); s += pv[j]; }
#pragma unroll
    for (int off = 32; off; off >>= 1) s += __shfl_xor(s, off);
    if ((tx & 63) == 0) redS[tt][(tx >> 6) & 3] = s;
  }
  __syncthreads();
  if (tx < 512) {
    const float s = (redS[tt][0] + redS[tt][1]) + (redS[tt][2] + redS[tt][3]);
    const float rinv = 1.0f / s;
    float* arow = attn + (size_t)(bt0 + tt) * SE + q * 4;
    *(float4*)arow = make_float4(pv[0] * rinv, pv[1] * rinv, pv[2] * rinv, pv[3] * rinv);
  }
}

// ---------------------------------------------------------------------------
// K3: partial context over s-chunks of 128. grid = sc(8) x tg(16) x b(4) = 512.
// WG: 8 t-rows x all 512 d; thread = (d quad = (tx&127)*4, t-half = tx>>7 ->
// 4 rows). Per s: 1 float4 enc load + 4 wave-uniform LDS reads + 16 FMA.
__global__ __launch_bounds__(256, 2) void k_ctx_part(const float* __restrict__ attn,
                                                     const float* __restrict__ enc,
                                                     float* __restrict__ part) {
  __shared__ __align__(16) float at[8][128];
  const int wg = blockIdx.x;
  const int sch = wg & 7;
  const int tg = (wg >> 3) & 15;
  const int b = wg >> 7;
  const int tx = threadIdx.x;
  const int sbeg = sch * 128;
  {
    const int i = tx >> 5, c = (tx & 31) * 4;   // 8 rows x 32 float4
    *(float4*)&at[i][c] =
        *(const float4*)(attn + (size_t)(b * TD + tg * 8 + i) * SE + sbeg + c);
  }
  __syncthreads();
  const int d0 = (tx & 127) * 4;
  const int th = tx >> 7;               // 0/1: rows th*4 .. th*4+3 (wave-uniform)
  const float* ep = enc + ((size_t)b * SE + sbeg) * DD + d0;
  float4 acc[4] = {};
  for (int s = 0; s < 128; ++s) {
    const float4 ev = *(const float4*)(ep + (size_t)s * DD);
#pragma unroll
    for (int i = 0; i < 4; ++i) {
      const float aij = at[th * 4 + i][s];
      acc[i].x = fmaf(aij, ev.x, acc[i].x);
      acc[i].y = fmaf(aij, ev.y, acc[i].y);
      acc[i].z = fmaf(aij, ev.z, acc[i].z);
      acc[i].w = fmaf(aij, ev.w, acc[i].w);
    }
  }
  float* pb = part + ((size_t)sch * (NB * TD) + b * TD + tg * 8 + th * 4) * DD + d0;
#pragma unroll
  for (int i = 0; i < 4; ++i)
    *(float4*)(pb + (size_t)i * DD) = acc[i];
}

// ---------------------------------------------------------------------------
// K4: ctx = sum of 8 partials. grid 256 x 256 thr, float4/thread.
__global__ __launch_bounds__(256, 2) void k_red(const float* __restrict__ part,
                                                float* __restrict__ ctx) {
  const size_t N = (size_t)NB * TD * DD;
  const size_t i = ((size_t)blockIdx.x * 256 + threadIdx.x) * 4;
  float4 o = *(const float4*)(part + i);
#pragma unroll
  for (int s = 1; s < SSPLIT; ++s) {
    const float4 q = *(const float4*)(part + (size_t)s * N + i);
    o.x += q.x; o.y += q.y; o.z += q.z; o.w += q.w;
  }
  *(float4*)(ctx + i) = o;
}

extern "C" void kernel_launch(void* const* d_in, const int* in_sizes, int n_in,
                              void* d_out, int out_size, void* d_ws, size_t ws_size,
                              hipStream_t stream) {
  const float* dec = (const float*)d_in[0];
  const float* enc = (const float*)d_in[1];
  const float* W1  = (const float*)d_in[2];
  const float* b1  = (const float*)d_in[3];
  const float* W2  = (const float*)d_in[4];
  const float* b2  = (const float*)d_in[5];
  const float* v   = (const float*)d_in[6];
  // d_in[7] = v_b: skipped — softmax is invariant to a uniform score shift.

  float* ctx  = (float*)d_out;                        // [4,128,512]
  float* attn = (float*)d_out + (size_t)NB * TD * DD; // [4,128,1024]

  float* ws    = (float*)d_ws;
  float* wencT = ws;                                  // [4][128][1024] 2 MB
  float* wdec  = wencT + (size_t)NB * UN * SE;        // [512][128] 256 KB
  // scratch shared in time: proj partials (9 MB) then ctx partials (8 MB)
  float* scratch = wdec + (size_t)NB * TD * UN;
  float* projpart = scratch;                          // [4][4608][128]
  float* ctxpart  = scratch;                          // [8][512][512]

  hipLaunchKernelGGL(k_proj_part, dim3(144, KSPLIT), dim3(256), 0, stream,
                     enc, dec, W1, W2, projpart);
  hipLaunchKernelGGL(k_redT, dim3(288), dim3(256), 0, stream,
                     projpart, b1, b2, wencT, wdec);
  hipLaunchKernelGGL(k_score, dim3(256), dim3(1024), 0, stream,
                     wdec, v, wencT, attn);
  hipLaunchKernelGGL(k_ctx_part, dim3(512), dim3(256), 0, stream, attn, enc, ctxpart);
  hipLaunchKernelGGL(k_red, dim3(256), dim3(256), 0, stream, ctxpart, ctx);
}